// Round 4
// baseline (929.385 us; speedup 1.0000x reference)
//
#include <hip/hip_runtime.h>
#include <hip/hip_bf16.h>

#define LRELU 0.2f
#define BN_INVS 0.99999500003749968f  // 1/sqrt(1+1e-5)

// ---------------------------------------------------------------- CSR build
__global__ __launch_bounds__(256) void k_initdeg(int* deg, int n) {
    int i = blockIdx.x * 256 + threadIdx.x;
    if (i < n) deg[i] = 1;  // self-loop contributes 1
}

__global__ __launch_bounds__(256) void k_count(const int* __restrict__ ei, int* deg, int E) {
    int e = blockIdx.x * 256 + threadIdx.x;
    if (e < E) atomicAdd(&deg[ei[E + e]], 1);
}

__global__ __launch_bounds__(1024) void k_scan1(const int* __restrict__ deg, int* row_ptr,
                                                int* bsum, int n) {
    __shared__ int sm[1024];
    int t = threadIdx.x, g = blockIdx.x * 1024 + t;
    sm[t] = (g < n) ? deg[g] : 0;
    __syncthreads();
    for (int off = 1; off < 1024; off <<= 1) {
        int x = (t >= off) ? sm[t - off] : 0;
        __syncthreads();
        sm[t] += x;
        __syncthreads();
    }
    if (g < n) row_ptr[g + 1] = sm[t];
    if (t == 1023) bsum[blockIdx.x] = sm[t];
}

__global__ void k_scan2(const int* bsum, int* boff, int nb) {
    if (threadIdx.x == 0 && blockIdx.x == 0) {
        int s = 0;
        for (int i = 0; i < nb; ++i) { boff[i] = s; s += bsum[i]; }
    }
}

__global__ __launch_bounds__(1024) void k_scan3(int* row_ptr, const int* boff, int n) {
    int g = blockIdx.x * 1024 + threadIdx.x;
    if (g < n) row_ptr[g + 1] += boff[blockIdx.x];
    if (g == 0) row_ptr[0] = 0;
}

__global__ __launch_bounds__(256) void k_cursor(const int* __restrict__ rp, int* cur, int n) {
    int i = blockIdx.x * 256 + threadIdx.x;
    if (i < n) cur[i] = rp[i];
}

__global__ __launch_bounds__(256) void k_scatter(const int* __restrict__ ei, int* cur, int* col,
                                                 int E, int n) {
    int t = blockIdx.x * 256 + threadIdx.x;
    if (t < E) {
        int s = ei[t], d = ei[E + t];
        int p = atomicAdd(&cur[d], 1);
        col[p] = s;
    } else if (t < E + n) {
        int v = t - E;
        int p = atomicAdd(&cur[v], 1);
        col[p] = v;
    }
}

// ---------------------------------------------------------------- node encoder
__global__ __launch_bounds__(256) void k_node_enc(const float* __restrict__ x,
                                                  const float* __restrict__ W,
                                                  const float* __restrict__ b,
                                                  float* __restrict__ h, int n) {
    __shared__ float Ws[1280];
    __shared__ float bs[128];
    for (int i = threadIdx.x; i < 1280; i += 256) Ws[i] = W[i];
    if (threadIdx.x < 128) bs[threadIdx.x] = b[threadIdx.x];
    __syncthreads();
    int idx = blockIdx.x * 256 + threadIdx.x;  // over n*32
    if (idx >= n * 32) return;
    int v = idx >> 5, q = idx & 31;
    float xr[10];
#pragma unroll
    for (int i = 0; i < 10; ++i) xr[i] = x[v * 10 + i];
    float o[4];
#pragma unroll
    for (int j = 0; j < 4; ++j) {
        int c = q * 4 + j;
        float s = bs[c];
#pragma unroll
        for (int i = 0; i < 10; ++i) s += xr[i] * Ws[i * 128 + c];
        o[j] = fmaxf(s, 0.f);
    }
    *(float4*)(h + (size_t)v * 128 + q * 4) = make_float4(o[0], o[1], o[2], o[3]);
}

// ---------------------------------------------------------------- tiled fp32 GEMM, K=128
// C[n][M] = A[n][128] @ B[128][M] (+bias, relu optional). 128x128 tile, 8x8/thread.
template <int M, bool ADD_BIAS, bool RELU>
__global__ __launch_bounds__(256) void k_gemm128(const float* __restrict__ A,
                                                 const float* __restrict__ B,
                                                 const float* __restrict__ bias,
                                                 float* __restrict__ C, int n) {
    constexpr int NG = M / 64;       // column groups of 64 (1 or 2)
    __shared__ float AsT[32][133];   // transposed A tile: [k][row]; 133 => 2 lanes/bank on store
    __shared__ float Bs[32][M];
    int tid = threadIdx.x;
    int row0 = blockIdx.x * 128;
    int ct = tid & 15, rt = tid >> 4;  // 16 col-threads x 16 row-threads
    float4 acc[8][NG];
#pragma unroll
    for (int i = 0; i < 8; ++i)
#pragma unroll
        for (int g = 0; g < NG; ++g) acc[i][g] = make_float4(0.f, 0.f, 0.f, 0.f);

    for (int kc = 0; kc < 128; kc += 32) {
        // stage A (128 rows x 32 k), transposed into LDS
#pragma unroll
        for (int i = 0; i < 4; ++i) {
            int f = tid + i * 256;       // 0..1023
            int r = f >> 3;              // 0..127
            int kq = (f & 7) * 4;        // 0..28
            float4 v = make_float4(0.f, 0.f, 0.f, 0.f);
            int gr = row0 + r;
            if (gr < n) v = *(const float4*)(A + (size_t)gr * 128 + kc + kq);
            AsT[kq + 0][r] = v.x;
            AsT[kq + 1][r] = v.y;
            AsT[kq + 2][r] = v.z;
            AsT[kq + 3][r] = v.w;
        }
        // stage B (32 k x M cols)
#pragma unroll
        for (int i = 0; i < M / 32; ++i) {
            int f = tid + i * 256;
            int r = f / (M / 4), c4 = (f % (M / 4)) * 4;
            *(float4*)(&Bs[r][c4]) = *(const float4*)(B + (size_t)(kc + r) * M + c4);
        }
        __syncthreads();
#pragma unroll
        for (int k = 0; k < 32; ++k) {
            float4 a0 = *(const float4*)(&AsT[k][rt * 8]);
            float4 a1 = *(const float4*)(&AsT[k][rt * 8 + 4]);
            float av[8] = {a0.x, a0.y, a0.z, a0.w, a1.x, a1.y, a1.z, a1.w};
#pragma unroll
            for (int g = 0; g < NG; ++g) {
                float4 bv = *(const float4*)(&Bs[k][g * 64 + ct * 4]);
#pragma unroll
                for (int i = 0; i < 8; ++i) {
                    acc[i][g].x += av[i] * bv.x;
                    acc[i][g].y += av[i] * bv.y;
                    acc[i][g].z += av[i] * bv.z;
                    acc[i][g].w += av[i] * bv.w;
                }
            }
        }
        __syncthreads();
    }
    float4 bb[NG];
    if (ADD_BIAS) {
#pragma unroll
        for (int g = 0; g < NG; ++g) bb[g] = *(const float4*)(bias + g * 64 + ct * 4);
    }
#pragma unroll
    for (int i = 0; i < 8; ++i) {
        int gr = row0 + rt * 8 + i;
        if (gr < n) {
#pragma unroll
            for (int g = 0; g < NG; ++g) {
                float4 v = acc[i][g];
                if (ADD_BIAS) {
                    v.x += bb[g].x; v.y += bb[g].y; v.z += bb[g].z; v.w += bb[g].w;
                }
                if (RELU) {
                    v.x = fmaxf(v.x, 0.f); v.y = fmaxf(v.y, 0.f);
                    v.z = fmaxf(v.z, 0.f); v.w = fmaxf(v.w, 0.f);
                }
                *(float4*)(C + (size_t)gr * M + g * 64 + ct * 4) = v;
            }
        }
    }
}

// ---------------------------------------------------------------- attention logits per node
template <int HEADS>
__global__ __launch_bounds__(256) void k_al(const float* __restrict__ hw,
                                            const float* __restrict__ asrc,
                                            const float* __restrict__ adst,
                                            float* __restrict__ al_s, float* __restrict__ al_d,
                                            int n) {
    int wid = (blockIdx.x * 256 + threadIdx.x) >> 6;
    int l = threadIdx.x & 63;
    if (wid >= n) return;
    float2 hv = *(const float2*)(hw + (size_t)wid * 128 + 2 * l);
    int c0 = 2 * l;
    if (HEADS == 4) {
        int h = l >> 4, dd = c0 & 31;
        float s = hv.x * asrc[h * 32 + dd] + hv.y * asrc[h * 32 + dd + 1];
        float d = hv.x * adst[h * 32 + dd] + hv.y * adst[h * 32 + dd + 1];
#pragma unroll
        for (int off = 1; off < 16; off <<= 1) {
            s += __shfl_xor(s, off);
            d += __shfl_xor(d, off);
        }
        if ((l & 15) == 0) {
            al_s[wid * 4 + h] = s;
            al_d[wid * 4 + h] = d;
        }
    } else {
        float s = hv.x * asrc[c0] + hv.y * asrc[c0 + 1];
        float d = hv.x * adst[c0] + hv.y * adst[c0 + 1];
#pragma unroll
        for (int off = 1; off < 64; off <<= 1) {
            s += __shfl_xor(s, off);
            d += __shfl_xor(d, off);
        }
        if (l == 0) {
            al_s[wid] = s;
            al_d[wid] = d;
        }
    }
}

// ------------------------------------------- fused segment softmax + aggregation + bias/BN/ReLU
// One wave per destination node. Pass 1: online (max,sum) of leaky-relu logits,
// lane-strided over edges. Pass 2: half-wave per edge, 32 lanes x float4 channel
// gather, alpha recomputed inline; 1/s folded into epilogue.
template <int HEADS>
__global__ __launch_bounds__(256) void k_softagg(const int* __restrict__ rp,
                                                 const int* __restrict__ col,
                                                 const float* __restrict__ al_s,
                                                 const float* __restrict__ al_d,
                                                 const float* __restrict__ hw,
                                                 const float* __restrict__ gb,
                                                 const float* __restrict__ bng,
                                                 const float* __restrict__ bnb,
                                                 float* __restrict__ hout, int n) {
    int v = (blockIdx.x * 256 + threadIdx.x) >> 6;
    int l = threadIdx.x & 63;
    if (v >= n) return;
    int start = rp[v], end = rp[v + 1];

    float ad[HEADS], m[HEADS], s[HEADS];
#pragma unroll
    for (int h = 0; h < HEADS; ++h) {
        ad[h] = al_d[v * HEADS + h];
        m[h] = -1e30f;
        s[h] = 0.f;
    }

    // ---- pass 1: online max/sum, lane-strided
    for (int p = start + l; p < end; p += 64) {
        int src = col[p];
        float asv[HEADS];
        if (HEADS == 4) {
            float4 t4 = *(const float4*)(al_s + (size_t)src * 4);
            asv[0] = t4.x; asv[1] = t4.y; asv[2] = t4.z; asv[3] = t4.w;
        } else {
            asv[0] = al_s[src];
        }
#pragma unroll
        for (int h = 0; h < HEADS; ++h) {
            float e = asv[h] + ad[h];
            e = (e >= 0.f) ? e : LRELU * e;
            float nm = fmaxf(m[h], e);
            s[h] = s[h] * __expf(m[h] - nm) + __expf(e - nm);
            m[h] = nm;
        }
    }
#pragma unroll
    for (int off = 1; off < 64; off <<= 1) {
#pragma unroll
        for (int h = 0; h < HEADS; ++h) {
            float om = __shfl_xor(m[h], off), os = __shfl_xor(s[h], off);
            float nm = fmaxf(m[h], om);
            s[h] = s[h] * __expf(m[h] - nm) + os * __expf(om - nm);
            m[h] = nm;
        }
    }
    float inv[HEADS];
#pragma unroll
    for (int h = 0; h < HEADS; ++h) inv[h] = 1.f / (s[h] + 1e-16f);

    // ---- pass 2: half-wave per edge, float4 channels, x2 unroll (4 gathers in flight)
    int eh = l >> 5;       // which edge of the pair
    int li = l & 31;       // channel lane
    int c4 = 4 * li;
    int hd = (HEADS == 4) ? (li >> 3) : 0;
    float mh = m[hd], invh = inv[hd], adh = ad[hd];
    float4 acc = make_float4(0.f, 0.f, 0.f, 0.f);

    int p = start + eh;
    for (; p + 2 < end; p += 4) {
        int s0 = col[p], s1 = col[p + 2];
        float e0 = al_s[(size_t)s0 * HEADS + hd] + adh;
        float e1 = al_s[(size_t)s1 * HEADS + hd] + adh;
        e0 = (e0 >= 0.f) ? e0 : LRELU * e0;
        e1 = (e1 >= 0.f) ? e1 : LRELU * e1;
        float a0 = __expf(e0 - mh);
        float a1 = __expf(e1 - mh);
        float4 h0 = *(const float4*)(hw + (size_t)s0 * 128 + c4);
        float4 h1 = *(const float4*)(hw + (size_t)s1 * 128 + c4);
        acc.x += a0 * h0.x + a1 * h1.x;
        acc.y += a0 * h0.y + a1 * h1.y;
        acc.z += a0 * h0.z + a1 * h1.z;
        acc.w += a0 * h0.w + a1 * h1.w;
    }
    if (p < end) {
        int s0 = col[p];
        float e0 = al_s[(size_t)s0 * HEADS + hd] + adh;
        e0 = (e0 >= 0.f) ? e0 : LRELU * e0;
        float a0 = __expf(e0 - mh);
        float4 h0 = *(const float4*)(hw + (size_t)s0 * 128 + c4);
        acc.x += a0 * h0.x;
        acc.y += a0 * h0.y;
        acc.z += a0 * h0.z;
        acc.w += a0 * h0.w;
    }
    // combine the two half-wave partial sums
    acc.x += __shfl_xor(acc.x, 32);
    acc.y += __shfl_xor(acc.y, 32);
    acc.z += __shfl_xor(acc.z, 32);
    acc.w += __shfl_xor(acc.w, 32);

    if (l < 32) {
        float4 g4 = *(const float4*)(gb + c4);
        float4 bg = *(const float4*)(bng + c4);
        float4 bbv = *(const float4*)(bnb + c4);
        float4 o;
        o.x = fmaxf((acc.x * invh + g4.x) * (bg.x * BN_INVS) + bbv.x, 0.f);
        o.y = fmaxf((acc.y * invh + g4.y) * (bg.y * BN_INVS) + bbv.y, 0.f);
        o.z = fmaxf((acc.z * invh + g4.z) * (bg.z * BN_INVS) + bbv.z, 0.f);
        o.w = fmaxf((acc.w * invh + g4.w) * (bg.w * BN_INVS) + bbv.w, 0.f);
        *(float4*)(hout + (size_t)v * 128 + c4) = o;
    }
}

// ---------------------------------------------------------------- platform branch -> c1 bias vector
__global__ void k_pconst(const float* __restrict__ px, const float* __restrict__ pW,
                         const float* __restrict__ pb, const float* __restrict__ c1W,
                         const float* __restrict__ c1b, float* __restrict__ cvec) {
    __shared__ float p[64];
    int t = threadIdx.x;  // 128 threads
    if (t < 64) {
        float s = pb[t];
#pragma unroll
        for (int i = 0; i < 4; ++i) s += px[i] * pW[i * 64 + t];
        p[t] = fmaxf(s, 0.f);
    }
    __syncthreads();
    if (t < 128) {
        float s = c1b[t];
#pragma unroll
        for (int j = 0; j < 64; ++j) s += p[j] * c1W[(128 + j) * 128 + t];
        cvec[t] = s;
    }
}

// ---------------------------------------------------------------- final classifier 64 -> 3
__global__ __launch_bounds__(256) void k_c3(const float* __restrict__ h5,
                                            const float* __restrict__ W,
                                            const float* __restrict__ b, float* __restrict__ out,
                                            int n) {
    __shared__ float Ws[192];
    __shared__ float bs[3];
    if (threadIdx.x < 192) Ws[threadIdx.x] = W[threadIdx.x];
    if (threadIdx.x < 3) bs[threadIdx.x] = b[threadIdx.x];
    __syncthreads();
    int v = blockIdx.x * 256 + threadIdx.x;
    if (v >= n) return;
    float a0 = bs[0], a1 = bs[1], a2 = bs[2];
#pragma unroll
    for (int k4 = 0; k4 < 16; ++k4) {
        float4 xv = *(const float4*)(h5 + (size_t)v * 64 + k4 * 4);
        int k = k4 * 4;
        a0 += xv.x * Ws[k * 3 + 0] + xv.y * Ws[k * 3 + 3] + xv.z * Ws[k * 3 + 6] + xv.w * Ws[k * 3 + 9];
        a1 += xv.x * Ws[k * 3 + 1] + xv.y * Ws[k * 3 + 4] + xv.z * Ws[k * 3 + 7] + xv.w * Ws[k * 3 + 10];
        a2 += xv.x * Ws[k * 3 + 2] + xv.y * Ws[k * 3 + 5] + xv.z * Ws[k * 3 + 8] + xv.w * Ws[k * 3 + 11];
    }
    out[v * 3 + 0] = a0;
    out[v * 3 + 1] = a1;
    out[v * 3 + 2] = a2;
}

// ================================================================ launch
extern "C" void kernel_launch(void* const* d_in, const int* in_sizes, int n_in,
                              void* d_out, int out_size, void* d_ws, size_t ws_size,
                              hipStream_t stream) {
    const float* x      = (const float*)d_in[0];
    const int*   ei     = (const int*)d_in[1];
    const float* px     = (const float*)d_in[2];
    const float* node_W = (const float*)d_in[3];
    const float* node_b = (const float*)d_in[4];
    const float* plat_W = (const float*)d_in[5];
    const float* plat_b = (const float*)d_in[6];
    const float* g1_W = (const float*)d_in[7];
    const float* g1_as = (const float*)d_in[8];
    const float* g1_ad = (const float*)d_in[9];
    const float* g1_b = (const float*)d_in[10];
    const float* g2_W = (const float*)d_in[11];
    const float* g2_as = (const float*)d_in[12];
    const float* g2_ad = (const float*)d_in[13];
    const float* g2_b = (const float*)d_in[14];
    const float* g3_W = (const float*)d_in[15];
    const float* g3_as = (const float*)d_in[16];
    const float* g3_ad = (const float*)d_in[17];
    const float* g3_b = (const float*)d_in[18];
    const float* bn1_g = (const float*)d_in[19];
    const float* bn1_b = (const float*)d_in[20];
    const float* bn2_g = (const float*)d_in[21];
    const float* bn2_b = (const float*)d_in[22];
    const float* bn3_g = (const float*)d_in[23];
    const float* bn3_b = (const float*)d_in[24];
    const float* c1_W = (const float*)d_in[25];
    const float* c1_b = (const float*)d_in[26];
    const float* c2_W = (const float*)d_in[27];
    const float* c2_b = (const float*)d_in[28];
    const float* c3_W = (const float*)d_in[29];
    const float* c3_b = (const float*)d_in[30];

    const int N = in_sizes[0] / 10;
    const int E = in_sizes[1] / 2;
    const int ET = E + N;  // edges incl. self loops

    // workspace carve-up (~60 MB)
    char* w = (char*)d_ws;
    auto alloc = [&](size_t bytes) {
        void* p = (void*)w;
        w += (bytes + 255) & ~(size_t)255;
        return p;
    };
    int*   col     = (int*)alloc((size_t)ET * 4);
    int*   deg     = (int*)alloc((size_t)N * 4);  // reused as scatter cursor
    int*   row_ptr = (int*)alloc((size_t)(N + 1) * 4);
    int*   bsum    = (int*)alloc(256 * 4);
    int*   boff    = (int*)alloc(256 * 4);
    float* al_s    = (float*)alloc((size_t)N * 4 * 4);
    float* al_d    = (float*)alloc((size_t)N * 4 * 4);
    float* bufA    = (float*)alloc((size_t)N * 128 * 4);
    float* bufB    = (float*)alloc((size_t)N * 128 * 4);
    float* cvec    = (float*)alloc(128 * 4);
    float* out     = (float*)d_out;

    const int NB = (N + 1023) / 1024;

    // ---- CSR build (dst-sorted; shared by all 3 GAT layers)
    k_initdeg<<<(N + 255) / 256, 256, 0, stream>>>(deg, N);
    k_count<<<(E + 255) / 256, 256, 0, stream>>>(ei, deg, E);
    k_scan1<<<NB, 1024, 0, stream>>>(deg, row_ptr, bsum, N);
    k_scan2<<<1, 64, 0, stream>>>(bsum, boff, NB);
    k_scan3<<<NB, 1024, 0, stream>>>(row_ptr, boff, N);
    k_cursor<<<(N + 255) / 256, 256, 0, stream>>>(row_ptr, deg, N);
    k_scatter<<<(ET + 255) / 256, 256, 0, stream>>>(ei, deg, col, E, N);

    // ---- node encoder
    k_node_enc<<<(N * 32 + 255) / 256, 256, 0, stream>>>(x, node_W, node_b, bufA, N);

    const int gGemm = (N + 127) / 128;
    const int gWave = (N * 64 + 255) / 256;  // one wave per node

    // ---- GAT layer 1 (heads=4)
    k_gemm128<128, false, false><<<gGemm, 256, 0, stream>>>(bufA, g1_W, nullptr, bufB, N);
    k_al<4><<<gWave, 256, 0, stream>>>(bufB, g1_as, g1_ad, al_s, al_d, N);
    k_softagg<4><<<gWave, 256, 0, stream>>>(row_ptr, col, al_s, al_d, bufB, g1_b, bn1_g, bn1_b, bufA, N);

    // ---- GAT layer 2 (heads=4)
    k_gemm128<128, false, false><<<gGemm, 256, 0, stream>>>(bufA, g2_W, nullptr, bufB, N);
    k_al<4><<<gWave, 256, 0, stream>>>(bufB, g2_as, g2_ad, al_s, al_d, N);
    k_softagg<4><<<gWave, 256, 0, stream>>>(row_ptr, col, al_s, al_d, bufB, g2_b, bn2_g, bn2_b, bufA, N);

    // ---- GAT layer 3 (heads=1)
    k_gemm128<128, false, false><<<gGemm, 256, 0, stream>>>(bufA, g3_W, nullptr, bufB, N);
    k_al<1><<<gWave, 256, 0, stream>>>(bufB, g3_as, g3_ad, al_s, al_d, N);
    k_softagg<1><<<gWave, 256, 0, stream>>>(row_ptr, col, al_s, al_d, bufB, g3_b, bn3_g, bn3_b, bufA, N);

    // ---- platform branch folded into c1 bias
    k_pconst<<<1, 128, 0, stream>>>(px, plat_W, plat_b, c1_W, c1_b, cvec);

    // ---- classifier (bufA [N,128] -> bufB [N,128] -> bufA reused as [N,64] -> out)
    k_gemm128<128, true, true><<<gGemm, 256, 0, stream>>>(bufA, c1_W, cvec, bufB, N);
    k_gemm128<64, true, true><<<gGemm, 256, 0, stream>>>(bufB, c2_W, c2_b, bufA, N);
    k_c3<<<(N + 255) / 256, 256, 0, stream>>>(bufA, c3_W, c3_b, out, N);
}

// Round 7
// 873.538 us; speedup vs baseline: 1.0639x; 1.0639x over previous
//
#include <hip/hip_runtime.h>
#include <hip/hip_bf16.h>

#define LRELU 0.2f
#define BN_INVS 0.99999500003749968f  // 1/sqrt(1+1e-5)

// ---------------------------------------------------------------- CSR build
__global__ __launch_bounds__(256) void k_initdeg(int* deg, int n) {
    int i = blockIdx.x * 256 + threadIdx.x;
    if (i < n) deg[i] = 1;  // self-loop contributes 1
}

__global__ __launch_bounds__(256) void k_count(const int* __restrict__ ei, int* deg, int E) {
    int e = blockIdx.x * 256 + threadIdx.x;
    if (e < E) atomicAdd(&deg[ei[E + e]], 1);
}

__global__ __launch_bounds__(1024) void k_scan1(const int* __restrict__ deg, int* row_ptr,
                                                int* bsum, int n) {
    __shared__ int sm[1024];
    int t = threadIdx.x, g = blockIdx.x * 1024 + t;
    sm[t] = (g < n) ? deg[g] : 0;
    __syncthreads();
    for (int off = 1; off < 1024; off <<= 1) {
        int x = (t >= off) ? sm[t - off] : 0;
        __syncthreads();
        sm[t] += x;
        __syncthreads();
    }
    if (g < n) row_ptr[g + 1] = sm[t];
    if (t == 1023) bsum[blockIdx.x] = sm[t];
}

__global__ void k_scan2(const int* bsum, int* boff, int nb) {
    if (threadIdx.x == 0 && blockIdx.x == 0) {
        int s = 0;
        for (int i = 0; i < nb; ++i) { boff[i] = s; s += bsum[i]; }
    }
}

__global__ __launch_bounds__(1024) void k_scan3(int* row_ptr, const int* boff, int n) {
    int g = blockIdx.x * 1024 + threadIdx.x;
    if (g < n) row_ptr[g + 1] += boff[blockIdx.x];
    if (g == 0) row_ptr[0] = 0;
}

__global__ __launch_bounds__(256) void k_cursor(const int* __restrict__ rp, int* cur, int n) {
    int i = blockIdx.x * 256 + threadIdx.x;
    if (i < n) cur[i] = rp[i];
}

// XCD-range-partitioned scatter: group g = blockIdx&7 handles dst in [g*W, g*W+W).
// Each group's col write-window (~825 KB) stays L2-resident on its XCD, so cache
// lines are fully assembled before write-back (vs 64B line dirtied per 4B write).
__global__ __launch_bounds__(256) void k_scatter(const int* __restrict__ ei, int* cur, int* col,
                                                 int E, int n) {
    int g = blockIdx.x & 7;
    int W = (n + 7) >> 3;
    int lo = g * W;
    int hi = min(n, lo + W);
    int nb = gridDim.x >> 3;   // blocks per group
    int bi = blockIdx.x >> 3;  // block index within group
    int stride = nb * 256;
    for (int t = bi * 256 + threadIdx.x; t < E; t += stride) {
        int d = ei[E + t];
        if (d >= lo && d < hi) {
            int p = atomicAdd(&cur[d], 1);
            col[p] = ei[t];
        }
    }
    // self-loops for this group's node range
    for (int v = lo + bi * 256 + threadIdx.x; v < hi; v += stride) {
        int p = atomicAdd(&cur[v], 1);
        col[p] = v;
    }
}

// ---------------------------------------------------------------- node encoder
__global__ __launch_bounds__(256) void k_node_enc(const float* __restrict__ x,
                                                  const float* __restrict__ W,
                                                  const float* __restrict__ b,
                                                  float* __restrict__ h, int n) {
    __shared__ float Ws[1280];
    __shared__ float bs[128];
    for (int i = threadIdx.x; i < 1280; i += 256) Ws[i] = W[i];
    if (threadIdx.x < 128) bs[threadIdx.x] = b[threadIdx.x];
    __syncthreads();
    int idx = blockIdx.x * 256 + threadIdx.x;  // over n*32
    if (idx >= n * 32) return;
    int v = idx >> 5, q = idx & 31;
    float xr[10];
#pragma unroll
    for (int i = 0; i < 10; ++i) xr[i] = x[v * 10 + i];
    float o[4];
#pragma unroll
    for (int j = 0; j < 4; ++j) {
        int c = q * 4 + j;
        float s = bs[c];
#pragma unroll
        for (int i = 0; i < 10; ++i) s += xr[i] * Ws[i * 128 + c];
        o[j] = fmaxf(s, 0.f);
    }
    *(float4*)(h + (size_t)v * 128 + q * 4) = make_float4(o[0], o[1], o[2], o[3]);
}

// ---------------------------------------------------------------- tiled fp32 GEMM, K=128
// C[n][M] = A[n][128] @ B[128][M] (+bias, relu optional). 128x128 tile, 8x8/thread.
template <int M, bool ADD_BIAS, bool RELU>
__global__ __launch_bounds__(256) void k_gemm128(const float* __restrict__ A,
                                                 const float* __restrict__ B,
                                                 const float* __restrict__ bias,
                                                 float* __restrict__ C, int n) {
    constexpr int NG = M / 64;       // column groups of 64 (1 or 2)
    __shared__ float AsT[32][133];   // transposed A tile: [k][row]; 133 => 2 lanes/bank on store
    __shared__ float Bs[32][M];
    int tid = threadIdx.x;
    int row0 = blockIdx.x * 128;
    int ct = tid & 15, rt = tid >> 4;  // 16 col-threads x 16 row-threads
    float4 acc[8][NG];
#pragma unroll
    for (int i = 0; i < 8; ++i)
#pragma unroll
        for (int g = 0; g < NG; ++g) acc[i][g] = make_float4(0.f, 0.f, 0.f, 0.f);

    for (int kc = 0; kc < 128; kc += 32) {
        // stage A (128 rows x 32 k), transposed into LDS
#pragma unroll
        for (int i = 0; i < 4; ++i) {
            int f = tid + i * 256;       // 0..1023
            int r = f >> 3;              // 0..127
            int kq = (f & 7) * 4;        // 0..28
            float4 v = make_float4(0.f, 0.f, 0.f, 0.f);
            int gr = row0 + r;
            if (gr < n) v = *(const float4*)(A + (size_t)gr * 128 + kc + kq);
            AsT[kq + 0][r] = v.x;
            AsT[kq + 1][r] = v.y;
            AsT[kq + 2][r] = v.z;
            AsT[kq + 3][r] = v.w;
        }
        // stage B (32 k x M cols)
#pragma unroll
        for (int i = 0; i < M / 32; ++i) {
            int f = tid + i * 256;
            int r = f / (M / 4), c4 = (f % (M / 4)) * 4;
            *(float4*)(&Bs[r][c4]) = *(const float4*)(B + (size_t)(kc + r) * M + c4);
        }
        __syncthreads();
#pragma unroll
        for (int k = 0; k < 32; ++k) {
            float4 a0 = *(const float4*)(&AsT[k][rt * 8]);
            float4 a1 = *(const float4*)(&AsT[k][rt * 8 + 4]);
            float av[8] = {a0.x, a0.y, a0.z, a0.w, a1.x, a1.y, a1.z, a1.w};
#pragma unroll
            for (int g = 0; g < NG; ++g) {
                float4 bv = *(const float4*)(&Bs[k][g * 64 + ct * 4]);
#pragma unroll
                for (int i = 0; i < 8; ++i) {
                    acc[i][g].x += av[i] * bv.x;
                    acc[i][g].y += av[i] * bv.y;
                    acc[i][g].z += av[i] * bv.z;
                    acc[i][g].w += av[i] * bv.w;
                }
            }
        }
        __syncthreads();
    }
    float4 bb[NG];
    if (ADD_BIAS) {
#pragma unroll
        for (int g = 0; g < NG; ++g) bb[g] = *(const float4*)(bias + g * 64 + ct * 4);
    }
#pragma unroll
    for (int i = 0; i < 8; ++i) {
        int gr = row0 + rt * 8 + i;
        if (gr < n) {
#pragma unroll
            for (int g = 0; g < NG; ++g) {
                float4 v = acc[i][g];
                if (ADD_BIAS) {
                    v.x += bb[g].x; v.y += bb[g].y; v.z += bb[g].z; v.w += bb[g].w;
                }
                if (RELU) {
                    v.x = fmaxf(v.x, 0.f); v.y = fmaxf(v.y, 0.f);
                    v.z = fmaxf(v.z, 0.f); v.w = fmaxf(v.w, 0.f);
                }
                *(float4*)(C + (size_t)gr * M + g * 64 + ct * 4) = v;
            }
        }
    }
}

// ---------------------------------------------------------------- attention logits per node
template <int HEADS>
__global__ __launch_bounds__(256) void k_al(const float* __restrict__ hw,
                                            const float* __restrict__ asrc,
                                            const float* __restrict__ adst,
                                            float* __restrict__ al_s, float* __restrict__ al_d,
                                            int n) {
    int wid = (blockIdx.x * 256 + threadIdx.x) >> 6;
    int l = threadIdx.x & 63;
    if (wid >= n) return;
    float2 hv = *(const float2*)(hw + (size_t)wid * 128 + 2 * l);
    int c0 = 2 * l;
    if (HEADS == 4) {
        int h = l >> 4, dd = c0 & 31;
        float s = hv.x * asrc[h * 32 + dd] + hv.y * asrc[h * 32 + dd + 1];
        float d = hv.x * adst[h * 32 + dd] + hv.y * adst[h * 32 + dd + 1];
#pragma unroll
        for (int off = 1; off < 16; off <<= 1) {
            s += __shfl_xor(s, off);
            d += __shfl_xor(d, off);
        }
        if ((l & 15) == 0) {
            al_s[wid * 4 + h] = s;
            al_d[wid * 4 + h] = d;
        }
    } else {
        float s = hv.x * asrc[c0] + hv.y * asrc[c0 + 1];
        float d = hv.x * adst[c0] + hv.y * adst[c0 + 1];
#pragma unroll
        for (int off = 1; off < 64; off <<= 1) {
            s += __shfl_xor(s, off);
            d += __shfl_xor(d, off);
        }
        if (l == 0) {
            al_s[wid] = s;
            al_d[wid] = d;
        }
    }
}

// ------------------------------------------- fused segment softmax + aggregation + bias/BN/ReLU
// One wave per destination node. Pass 1: online (max,sum) of leaky-relu logits, lane-strided;
// caches (src, post-leaky e[heads]) in wave-private LDS (CAP edges). Pass 2: half-wave per
// edge, float4 channel gather; reads src/e from LDS (2-level dep chain instead of 3);
// recompute fallback for idx>=CAP keeps correctness for any degree.
template <int HEADS>
__global__ __launch_bounds__(256) void k_softagg(const int* __restrict__ rp,
                                                 const int* __restrict__ col,
                                                 const float* __restrict__ al_s,
                                                 const float* __restrict__ al_d,
                                                 const float* __restrict__ hw,
                                                 const float* __restrict__ gb,
                                                 const float* __restrict__ bng,
                                                 const float* __restrict__ bnb,
                                                 float* __restrict__ hout, int n) {
    constexpr int CAP = 128;
    __shared__ int ss[4][CAP];
    __shared__ __align__(16) float se[4][CAP * HEADS];
    int v = (blockIdx.x * 256 + threadIdx.x) >> 6;
    int l = threadIdx.x & 63;
    int w = threadIdx.x >> 6;  // wave within block
    if (v >= n) return;
    int start = rp[v], end = rp[v + 1];

    float ad[HEADS], m[HEADS], s[HEADS];
#pragma unroll
    for (int h = 0; h < HEADS; ++h) {
        ad[h] = al_d[v * HEADS + h];
        m[h] = -1e30f;
        s[h] = 0.f;
    }

    // ---- pass 1: online max/sum, lane-strided; cache (src, e) in LDS
    for (int p = start + l; p < end; p += 64) {
        int src = col[p];
        float eh[HEADS];
        if (HEADS == 4) {
            float4 t4 = *(const float4*)(al_s + (size_t)src * 4);
            eh[0] = t4.x; eh[1] = t4.y; eh[2] = t4.z; eh[3] = t4.w;
        } else {
            eh[0] = al_s[src];
        }
#pragma unroll
        for (int h = 0; h < HEADS; ++h) {
            float e = eh[h] + ad[h];
            eh[h] = (e >= 0.f) ? e : LRELU * e;
        }
        int idx = p - start;
        if (idx < CAP) {
            ss[w][idx] = src;
            if (HEADS == 4)
                *(float4*)(&se[w][idx * 4]) = make_float4(eh[0], eh[1], eh[2], eh[3]);
            else
                se[w][idx] = eh[0];
        }
#pragma unroll
        for (int h = 0; h < HEADS; ++h) {
            float nm = fmaxf(m[h], eh[h]);
            s[h] = s[h] * __expf(m[h] - nm) + __expf(eh[h] - nm);
            m[h] = nm;
        }
    }
#pragma unroll
    for (int off = 1; off < 64; off <<= 1) {
#pragma unroll
        for (int h = 0; h < HEADS; ++h) {
            float om = __shfl_xor(m[h], off), os = __shfl_xor(s[h], off);
            float nm = fmaxf(m[h], om);
            s[h] = s[h] * __expf(m[h] - nm) + os * __expf(om - nm);
            m[h] = nm;
        }
    }
    float inv[HEADS];
#pragma unroll
    for (int h = 0; h < HEADS; ++h) inv[h] = 1.f / (s[h] + 1e-16f);

    // ---- pass 2: half-wave per edge, float4 channels, x2 unroll (4 gathers in flight)
    int ew = l >> 5;       // which edge of the pair
    int li = l & 31;       // channel lane
    int c4 = 4 * li;
    int hd = (HEADS == 4) ? (li >> 3) : 0;
    float mh = m[hd], invh = inv[hd], adh = ad[hd];
    float4 acc = make_float4(0.f, 0.f, 0.f, 0.f);

    int p = start + ew;
    for (; p + 2 < end; p += 4) {
        int i0 = p - start, i1 = i0 + 2;
        int s0, s1;
        float e0, e1;
        if (i0 < CAP) {
            s0 = ss[w][i0];
            e0 = (HEADS == 4) ? se[w][i0 * 4 + hd] : se[w][i0];
        } else {
            s0 = col[p];
            float t = al_s[(size_t)s0 * HEADS + hd] + adh;
            e0 = (t >= 0.f) ? t : LRELU * t;
        }
        if (i1 < CAP) {
            s1 = ss[w][i1];
            e1 = (HEADS == 4) ? se[w][i1 * 4 + hd] : se[w][i1];
        } else {
            s1 = col[p + 2];
            float t = al_s[(size_t)s1 * HEADS + hd] + adh;
            e1 = (t >= 0.f) ? t : LRELU * t;
        }
        float a0 = __expf(e0 - mh);
        float a1 = __expf(e1 - mh);
        float4 h0 = *(const float4*)(hw + (size_t)s0 * 128 + c4);
        float4 h1 = *(const float4*)(hw + (size_t)s1 * 128 + c4);
        acc.x += a0 * h0.x + a1 * h1.x;
        acc.y += a0 * h0.y + a1 * h1.y;
        acc.z += a0 * h0.z + a1 * h1.z;
        acc.w += a0 * h0.w + a1 * h1.w;
    }
    if (p < end) {
        int i0 = p - start;
        int s0;
        float e0;
        if (i0 < CAP) {
            s0 = ss[w][i0];
            e0 = (HEADS == 4) ? se[w][i0 * 4 + hd] : se[w][i0];
        } else {
            s0 = col[p];
            float t = al_s[(size_t)s0 * HEADS + hd] + adh;
            e0 = (t >= 0.f) ? t : LRELU * t;
        }
        float a0 = __expf(e0 - mh);
        float4 h0 = *(const float4*)(hw + (size_t)s0 * 128 + c4);
        acc.x += a0 * h0.x;
        acc.y += a0 * h0.y;
        acc.z += a0 * h0.z;
        acc.w += a0 * h0.w;
    }
    // combine the two half-wave partial sums
    acc.x += __shfl_xor(acc.x, 32);
    acc.y += __shfl_xor(acc.y, 32);
    acc.z += __shfl_xor(acc.z, 32);
    acc.w += __shfl_xor(acc.w, 32);

    if (l < 32) {
        float4 g4 = *(const float4*)(gb + c4);
        float4 bg = *(const float4*)(bng + c4);
        float4 bbv = *(const float4*)(bnb + c4);
        float4 o;
        o.x = fmaxf((acc.x * invh + g4.x) * (bg.x * BN_INVS) + bbv.x, 0.f);
        o.y = fmaxf((acc.y * invh + g4.y) * (bg.y * BN_INVS) + bbv.y, 0.f);
        o.z = fmaxf((acc.z * invh + g4.z) * (bg.z * BN_INVS) + bbv.z, 0.f);
        o.w = fmaxf((acc.w * invh + g4.w) * (bg.w * BN_INVS) + bbv.w, 0.f);
        *(float4*)(hout + (size_t)v * 128 + c4) = o;
    }
}

// ---------------------------------------------------------------- platform branch -> c1 bias vector
__global__ void k_pconst(const float* __restrict__ px, const float* __restrict__ pW,
                         const float* __restrict__ pb, const float* __restrict__ c1W,
                         const float* __restrict__ c1b, float* __restrict__ cvec) {
    __shared__ float p[64];
    int t = threadIdx.x;  // 128 threads
    if (t < 64) {
        float s = pb[t];
#pragma unroll
        for (int i = 0; i < 4; ++i) s += px[i] * pW[i * 64 + t];
        p[t] = fmaxf(s, 0.f);
    }
    __syncthreads();
    if (t < 128) {
        float s = c1b[t];
#pragma unroll
        for (int j = 0; j < 64; ++j) s += p[j] * c1W[(128 + j) * 128 + t];
        cvec[t] = s;
    }
}

// ---------------------------------------------------------------- final classifier 64 -> 3
__global__ __launch_bounds__(256) void k_c3(const float* __restrict__ h5,
                                            const float* __restrict__ W,
                                            const float* __restrict__ b, float* __restrict__ out,
                                            int n) {
    __shared__ float Ws[192];
    __shared__ float bs[3];
    if (threadIdx.x < 192) Ws[threadIdx.x] = W[threadIdx.x];
    if (threadIdx.x < 3) bs[threadIdx.x] = b[threadIdx.x];
    __syncthreads();
    int v = blockIdx.x * 256 + threadIdx.x;
    if (v >= n) return;
    float a0 = bs[0], a1 = bs[1], a2 = bs[2];
#pragma unroll
    for (int k4 = 0; k4 < 16; ++k4) {
        float4 xv = *(const float4*)(h5 + (size_t)v * 64 + k4 * 4);
        int k = k4 * 4;
        a0 += xv.x * Ws[k * 3 + 0] + xv.y * Ws[k * 3 + 3] + xv.z * Ws[k * 3 + 6] + xv.w * Ws[k * 3 + 9];
        a1 += xv.x * Ws[k * 3 + 1] + xv.y * Ws[k * 3 + 4] + xv.z * Ws[k * 3 + 7] + xv.w * Ws[k * 3 + 10];
        a2 += xv.x * Ws[k * 3 + 2] + xv.y * Ws[k * 3 + 5] + xv.z * Ws[k * 3 + 8] + xv.w * Ws[k * 3 + 11];
    }
    out[v * 3 + 0] = a0;
    out[v * 3 + 1] = a1;
    out[v * 3 + 2] = a2;
}

// ================================================================ launch
extern "C" void kernel_launch(void* const* d_in, const int* in_sizes, int n_in,
                              void* d_out, int out_size, void* d_ws, size_t ws_size,
                              hipStream_t stream) {
    const float* x      = (const float*)d_in[0];
    const int*   ei     = (const int*)d_in[1];
    const float* px     = (const float*)d_in[2];
    const float* node_W = (const float*)d_in[3];
    const float* node_b = (const float*)d_in[4];
    const float* plat_W = (const float*)d_in[5];
    const float* plat_b = (const float*)d_in[6];
    const float* g1_W = (const float*)d_in[7];
    const float* g1_as = (const float*)d_in[8];
    const float* g1_ad = (const float*)d_in[9];
    const float* g1_b = (const float*)d_in[10];
    const float* g2_W = (const float*)d_in[11];
    const float* g2_as = (const float*)d_in[12];
    const float* g2_ad = (const float*)d_in[13];
    const float* g2_b = (const float*)d_in[14];
    const float* g3_W = (const float*)d_in[15];
    const float* g3_as = (const float*)d_in[16];
    const float* g3_ad = (const float*)d_in[17];
    const float* g3_b = (const float*)d_in[18];
    const float* bn1_g = (const float*)d_in[19];
    const float* bn1_b = (const float*)d_in[20];
    const float* bn2_g = (const float*)d_in[21];
    const float* bn2_b = (const float*)d_in[22];
    const float* bn3_g = (const float*)d_in[23];
    const float* bn3_b = (const float*)d_in[24];
    const float* c1_W = (const float*)d_in[25];
    const float* c1_b = (const float*)d_in[26];
    const float* c2_W = (const float*)d_in[27];
    const float* c2_b = (const float*)d_in[28];
    const float* c3_W = (const float*)d_in[29];
    const float* c3_b = (const float*)d_in[30];

    const int N = in_sizes[0] / 10;
    const int E = in_sizes[1] / 2;
    const int ET = E + N;  // edges incl. self loops

    // workspace carve-up (~60 MB)
    char* w = (char*)d_ws;
    auto alloc = [&](size_t bytes) {
        void* p = (void*)w;
        w += (bytes + 255) & ~(size_t)255;
        return p;
    };
    int*   col     = (int*)alloc((size_t)ET * 4);
    int*   deg     = (int*)alloc((size_t)N * 4);  // reused as scatter cursor
    int*   row_ptr = (int*)alloc((size_t)(N + 1) * 4);
    int*   bsum    = (int*)alloc(256 * 4);
    int*   boff    = (int*)alloc(256 * 4);
    float* al_s    = (float*)alloc((size_t)N * 4 * 4);
    float* al_d    = (float*)alloc((size_t)N * 4 * 4);
    float* bufA    = (float*)alloc((size_t)N * 128 * 4);
    float* bufB    = (float*)alloc((size_t)N * 128 * 4);
    float* cvec    = (float*)alloc(128 * 4);
    float* out     = (float*)d_out;

    const int NB = (N + 1023) / 1024;

    // ---- CSR build (dst-sorted; shared by all 3 GAT layers)
    k_initdeg<<<(N + 255) / 256, 256, 0, stream>>>(deg, N);
    k_count<<<(E + 255) / 256, 256, 0, stream>>>(ei, deg, E);
    k_scan1<<<NB, 1024, 0, stream>>>(deg, row_ptr, bsum, N);
    k_scan2<<<1, 64, 0, stream>>>(bsum, boff, NB);
    k_scan3<<<NB, 1024, 0, stream>>>(row_ptr, boff, N);
    k_cursor<<<(N + 255) / 256, 256, 0, stream>>>(row_ptr, deg, N);
    k_scatter<<<832, 256, 0, stream>>>(ei, deg, col, E, N);  // 8 XCD groups x 104 blocks

    // ---- node encoder
    k_node_enc<<<(N * 32 + 255) / 256, 256, 0, stream>>>(x, node_W, node_b, bufA, N);

    const int gGemm = (N + 127) / 128;
    const int gWave = (N * 64 + 255) / 256;  // one wave per node

    // ---- GAT layer 1 (heads=4)
    k_gemm128<128, false, false><<<gGemm, 256, 0, stream>>>(bufA, g1_W, nullptr, bufB, N);
    k_al<4><<<gWave, 256, 0, stream>>>(bufB, g1_as, g1_ad, al_s, al_d, N);
    k_softagg<4><<<gWave, 256, 0, stream>>>(row_ptr, col, al_s, al_d, bufB, g1_b, bn1_g, bn1_b, bufA, N);

    // ---- GAT layer 2 (heads=4)
    k_gemm128<128, false, false><<<gGemm, 256, 0, stream>>>(bufA, g2_W, nullptr, bufB, N);
    k_al<4><<<gWave, 256, 0, stream>>>(bufB, g2_as, g2_ad, al_s, al_d, N);
    k_softagg<4><<<gWave, 256, 0, stream>>>(row_ptr, col, al_s, al_d, bufB, g2_b, bn2_g, bn2_b, bufA, N);

    // ---- GAT layer 3 (heads=1)
    k_gemm128<128, false, false><<<gGemm, 256, 0, stream>>>(bufA, g3_W, nullptr, bufB, N);
    k_al<1><<<gWave, 256, 0, stream>>>(bufB, g3_as, g3_ad, al_s, al_d, N);
    k_softagg<1><<<gWave, 256, 0, stream>>>(row_ptr, col, al_s, al_d, bufB, g3_b, bn3_g, bn3_b, bufA, N);

    // ---- platform branch folded into c1 bias
    k_pconst<<<1, 128, 0, stream>>>(px, plat_W, plat_b, c1_W, c1_b, cvec);

    // ---- classifier (bufA [N,128] -> bufB [N,128] -> bufA reused as [N,64] -> out)
    k_gemm128<128, true, true><<<gGemm, 256, 0, stream>>>(bufA, c1_W, cvec, bufB, N);
    k_gemm128<64, true, true><<<gGemm, 256, 0, stream>>>(bufB, c2_W, c2_b, bufA, N);
    k_c3<<<(N + 255) / 256, 256, 0, stream>>>(bufA, c3_W, c3_b, out, N);
}

// Round 8
// 738.685 us; speedup vs baseline: 1.2582x; 1.1826x over previous
//
#include <hip/hip_runtime.h>
#include <hip/hip_bf16.h>
#include <hip/hip_fp16.h>

#define LRELU 0.2f
#define BN_INVS 0.99999500003749968f  // 1/sqrt(1+1e-5)

// ---------------------------------------------------------------- CSR build
__global__ __launch_bounds__(256) void k_initdeg(int* deg, int n) {
    int i = blockIdx.x * 256 + threadIdx.x;
    if (i < n) deg[i] = 1;  // self-loop contributes 1
}

__global__ __launch_bounds__(256) void k_count(const int* __restrict__ ei, int* deg, int E) {
    int e = blockIdx.x * 256 + threadIdx.x;
    if (e < E) atomicAdd(&deg[ei[E + e]], 1);
}

__global__ __launch_bounds__(1024) void k_scan1(const int* __restrict__ deg, int* row_ptr,
                                                int* bsum, int n) {
    __shared__ int sm[1024];
    int t = threadIdx.x, g = blockIdx.x * 1024 + t;
    sm[t] = (g < n) ? deg[g] : 0;
    __syncthreads();
    for (int off = 1; off < 1024; off <<= 1) {
        int x = (t >= off) ? sm[t - off] : 0;
        __syncthreads();
        sm[t] += x;
        __syncthreads();
    }
    if (g < n) row_ptr[g + 1] = sm[t];
    if (t == 1023) bsum[blockIdx.x] = sm[t];
}

__global__ void k_scan2(const int* bsum, int* boff, int nb) {
    if (threadIdx.x == 0 && blockIdx.x == 0) {
        int s = 0;
        for (int i = 0; i < nb; ++i) { boff[i] = s; s += bsum[i]; }
    }
}

__global__ __launch_bounds__(1024) void k_scan3(int* row_ptr, const int* boff, int n) {
    int g = blockIdx.x * 1024 + threadIdx.x;
    if (g < n) row_ptr[g + 1] += boff[blockIdx.x];
    if (g == 0) row_ptr[0] = 0;
}

__global__ __launch_bounds__(256) void k_cursor(const int* __restrict__ rp, int* cur, int n) {
    int i = blockIdx.x * 256 + threadIdx.x;
    if (i < n) cur[i] = rp[i];
}

// XCD-range-partitioned scatter: group g = blockIdx&7 handles dst in [g*W, g*W+W).
__global__ __launch_bounds__(256) void k_scatter(const int* __restrict__ ei, int* cur, int* col,
                                                 int E, int n) {
    int g = blockIdx.x & 7;
    int W = (n + 7) >> 3;
    int lo = g * W;
    int hi = min(n, lo + W);
    int nb = gridDim.x >> 3;   // blocks per group
    int bi = blockIdx.x >> 3;  // block index within group
    int stride = nb * 256;
    for (int t = bi * 256 + threadIdx.x; t < E; t += stride) {
        int d = ei[E + t];
        if (d >= lo && d < hi) {
            int p = atomicAdd(&cur[d], 1);
            col[p] = ei[t];
        }
    }
    for (int v = lo + bi * 256 + threadIdx.x; v < hi; v += stride) {
        int p = atomicAdd(&cur[v], 1);
        col[p] = v;
    }
}

// ---------------------------------------------------------------- node encoder
__global__ __launch_bounds__(256) void k_node_enc(const float* __restrict__ x,
                                                  const float* __restrict__ W,
                                                  const float* __restrict__ b,
                                                  float* __restrict__ h, int n) {
    __shared__ float Ws[1280];
    __shared__ float bs[128];
    for (int i = threadIdx.x; i < 1280; i += 256) Ws[i] = W[i];
    if (threadIdx.x < 128) bs[threadIdx.x] = b[threadIdx.x];
    __syncthreads();
    int idx = blockIdx.x * 256 + threadIdx.x;  // over n*32
    if (idx >= n * 32) return;
    int v = idx >> 5, q = idx & 31;
    float xr[10];
#pragma unroll
    for (int i = 0; i < 10; ++i) xr[i] = x[v * 10 + i];
    float o[4];
#pragma unroll
    for (int j = 0; j < 4; ++j) {
        int c = q * 4 + j;
        float s = bs[c];
#pragma unroll
        for (int i = 0; i < 10; ++i) s += xr[i] * Ws[i * 128 + c];
        o[j] = fmaxf(s, 0.f);
    }
    *(float4*)(h + (size_t)v * 128 + q * 4) = make_float4(o[0], o[1], o[2], o[3]);
}

// ---------------------------------------------------------------- tiled fp32 GEMM, K=128
// C[n][M] = A[n][128] @ B[128][M] (+bias, relu optional). 128x128 tile, 8x8/thread.
// HALF_OUT: epilogue converts to fp16 (C reinterpreted as __half*) — halves the
// downstream gather traffic in k_softagg (values O(1), fp16 ulp 2^-11: safe).
template <int M, bool ADD_BIAS, bool RELU, bool HALF_OUT = false>
__global__ __launch_bounds__(256) void k_gemm128(const float* __restrict__ A,
                                                 const float* __restrict__ B,
                                                 const float* __restrict__ bias,
                                                 float* __restrict__ C, int n) {
    constexpr int NG = M / 64;       // column groups of 64 (1 or 2)
    __shared__ float AsT[32][133];   // transposed A tile: [k][row]; 133 => 2 lanes/bank on store
    __shared__ float Bs[32][M];
    int tid = threadIdx.x;
    int row0 = blockIdx.x * 128;
    int ct = tid & 15, rt = tid >> 4;  // 16 col-threads x 16 row-threads
    float4 acc[8][NG];
#pragma unroll
    for (int i = 0; i < 8; ++i)
#pragma unroll
        for (int g = 0; g < NG; ++g) acc[i][g] = make_float4(0.f, 0.f, 0.f, 0.f);

    for (int kc = 0; kc < 128; kc += 32) {
#pragma unroll
        for (int i = 0; i < 4; ++i) {
            int f = tid + i * 256;       // 0..1023
            int r = f >> 3;              // 0..127
            int kq = (f & 7) * 4;        // 0..28
            float4 v = make_float4(0.f, 0.f, 0.f, 0.f);
            int gr = row0 + r;
            if (gr < n) v = *(const float4*)(A + (size_t)gr * 128 + kc + kq);
            AsT[kq + 0][r] = v.x;
            AsT[kq + 1][r] = v.y;
            AsT[kq + 2][r] = v.z;
            AsT[kq + 3][r] = v.w;
        }
#pragma unroll
        for (int i = 0; i < M / 32; ++i) {
            int f = tid + i * 256;
            int r = f / (M / 4), c4 = (f % (M / 4)) * 4;
            *(float4*)(&Bs[r][c4]) = *(const float4*)(B + (size_t)(kc + r) * M + c4);
        }
        __syncthreads();
#pragma unroll
        for (int k = 0; k < 32; ++k) {
            float4 a0 = *(const float4*)(&AsT[k][rt * 8]);
            float4 a1 = *(const float4*)(&AsT[k][rt * 8 + 4]);
            float av[8] = {a0.x, a0.y, a0.z, a0.w, a1.x, a1.y, a1.z, a1.w};
#pragma unroll
            for (int g = 0; g < NG; ++g) {
                float4 bv = *(const float4*)(&Bs[k][g * 64 + ct * 4]);
#pragma unroll
                for (int i = 0; i < 8; ++i) {
                    acc[i][g].x += av[i] * bv.x;
                    acc[i][g].y += av[i] * bv.y;
                    acc[i][g].z += av[i] * bv.z;
                    acc[i][g].w += av[i] * bv.w;
                }
            }
        }
        __syncthreads();
    }
    float4 bb[NG];
    if (ADD_BIAS) {
#pragma unroll
        for (int g = 0; g < NG; ++g) bb[g] = *(const float4*)(bias + g * 64 + ct * 4);
    }
#pragma unroll
    for (int i = 0; i < 8; ++i) {
        int gr = row0 + rt * 8 + i;
        if (gr < n) {
#pragma unroll
            for (int g = 0; g < NG; ++g) {
                float4 v = acc[i][g];
                if (ADD_BIAS) {
                    v.x += bb[g].x; v.y += bb[g].y; v.z += bb[g].z; v.w += bb[g].w;
                }
                if (RELU) {
                    v.x = fmaxf(v.x, 0.f); v.y = fmaxf(v.y, 0.f);
                    v.z = fmaxf(v.z, 0.f); v.w = fmaxf(v.w, 0.f);
                }
                if (HALF_OUT) {
                    __half hb[4];
                    hb[0] = __float2half(v.x);
                    hb[1] = __float2half(v.y);
                    hb[2] = __float2half(v.z);
                    hb[3] = __float2half(v.w);
                    __half* C16 = reinterpret_cast<__half*>(C);
                    *(ushort4*)(C16 + (size_t)gr * M + g * 64 + ct * 4) = *(ushort4*)hb;
                } else {
                    *(float4*)(C + (size_t)gr * M + g * 64 + ct * 4) = v;
                }
            }
        }
    }
}

// ---------------------------------------------------------------- attention logits per node (fp16 h)
template <int HEADS>
__global__ __launch_bounds__(256) void k_al(const __half* __restrict__ hw,
                                            const float* __restrict__ asrc,
                                            const float* __restrict__ adst,
                                            float* __restrict__ al_s, float* __restrict__ al_d,
                                            int n) {
    int wid = (blockIdx.x * 256 + threadIdx.x) >> 6;
    int l = threadIdx.x & 63;
    if (wid >= n) return;
    unsigned raw = *(const unsigned*)(hw + (size_t)wid * 128 + 2 * l);
    __half2 hp = *reinterpret_cast<__half2*>(&raw);
    float2 hv = __half22float2(hp);
    int c0 = 2 * l;
    if (HEADS == 4) {
        int h = l >> 4, dd = c0 & 31;
        float s = hv.x * asrc[h * 32 + dd] + hv.y * asrc[h * 32 + dd + 1];
        float d = hv.x * adst[h * 32 + dd] + hv.y * adst[h * 32 + dd + 1];
#pragma unroll
        for (int off = 1; off < 16; off <<= 1) {
            s += __shfl_xor(s, off);
            d += __shfl_xor(d, off);
        }
        if ((l & 15) == 0) {
            al_s[wid * 4 + h] = s;
            al_d[wid * 4 + h] = d;
        }
    } else {
        float s = hv.x * asrc[c0] + hv.y * asrc[c0 + 1];
        float d = hv.x * adst[c0] + hv.y * adst[c0 + 1];
#pragma unroll
        for (int off = 1; off < 64; off <<= 1) {
            s += __shfl_xor(s, off);
            d += __shfl_xor(d, off);
        }
        if (l == 0) {
            al_s[wid] = s;
            al_d[wid] = d;
        }
    }
}

// ------------------------------------------- fused segment softmax + aggregation + bias/BN/ReLU
// One wave per destination node; LDS-cached (src, e); pass-2 gathers fp16 h rows
// (256 B/edge instead of 512) with fp32 accumulation.
template <int HEADS>
__global__ __launch_bounds__(256) void k_softagg(const int* __restrict__ rp,
                                                 const int* __restrict__ col,
                                                 const float* __restrict__ al_s,
                                                 const float* __restrict__ al_d,
                                                 const __half* __restrict__ hw,
                                                 const float* __restrict__ gb,
                                                 const float* __restrict__ bng,
                                                 const float* __restrict__ bnb,
                                                 float* __restrict__ hout, int n) {
    constexpr int CAP = 128;
    __shared__ int ss[4][CAP];
    __shared__ __align__(16) float se[4][CAP * HEADS];
    int v = (blockIdx.x * 256 + threadIdx.x) >> 6;
    int l = threadIdx.x & 63;
    int w = threadIdx.x >> 6;  // wave within block
    if (v >= n) return;
    int start = rp[v], end = rp[v + 1];

    float ad[HEADS], m[HEADS], s[HEADS];
#pragma unroll
    for (int h = 0; h < HEADS; ++h) {
        ad[h] = al_d[v * HEADS + h];
        m[h] = -1e30f;
        s[h] = 0.f;
    }

    // ---- pass 1: online max/sum, lane-strided; cache (src, e) in LDS
    for (int p = start + l; p < end; p += 64) {
        int src = col[p];
        float eh[HEADS];
        if (HEADS == 4) {
            float4 t4 = *(const float4*)(al_s + (size_t)src * 4);
            eh[0] = t4.x; eh[1] = t4.y; eh[2] = t4.z; eh[3] = t4.w;
        } else {
            eh[0] = al_s[src];
        }
#pragma unroll
        for (int h = 0; h < HEADS; ++h) {
            float e = eh[h] + ad[h];
            eh[h] = (e >= 0.f) ? e : LRELU * e;
        }
        int idx = p - start;
        if (idx < CAP) {
            ss[w][idx] = src;
            if (HEADS == 4)
                *(float4*)(&se[w][idx * 4]) = make_float4(eh[0], eh[1], eh[2], eh[3]);
            else
                se[w][idx] = eh[0];
        }
#pragma unroll
        for (int h = 0; h < HEADS; ++h) {
            float nm = fmaxf(m[h], eh[h]);
            s[h] = s[h] * __expf(m[h] - nm) + __expf(eh[h] - nm);
            m[h] = nm;
        }
    }
#pragma unroll
    for (int off = 1; off < 64; off <<= 1) {
#pragma unroll
        for (int h = 0; h < HEADS; ++h) {
            float om = __shfl_xor(m[h], off), os = __shfl_xor(s[h], off);
            float nm = fmaxf(m[h], om);
            s[h] = s[h] * __expf(m[h] - nm) + os * __expf(om - nm);
            m[h] = nm;
        }
    }
    float inv[HEADS];
#pragma unroll
    for (int h = 0; h < HEADS; ++h) inv[h] = 1.f / (s[h] + 1e-16f);

    // ---- pass 2: half-wave per edge, 4 fp16 channels/lane (8 B), x2 unroll
    int ew = l >> 5;       // which edge of the pair
    int li = l & 31;       // channel lane
    int c4 = 4 * li;
    int hd = (HEADS == 4) ? (li >> 3) : 0;
    float mh = m[hd], invh = inv[hd], adh = ad[hd];
    float4 acc = make_float4(0.f, 0.f, 0.f, 0.f);

    int p = start + ew;
    for (; p + 2 < end; p += 4) {
        int i0 = p - start, i1 = i0 + 2;
        int s0, s1;
        float e0, e1;
        if (i0 < CAP) {
            s0 = ss[w][i0];
            e0 = (HEADS == 4) ? se[w][i0 * 4 + hd] : se[w][i0];
        } else {
            s0 = col[p];
            float t = al_s[(size_t)s0 * HEADS + hd] + adh;
            e0 = (t >= 0.f) ? t : LRELU * t;
        }
        if (i1 < CAP) {
            s1 = ss[w][i1];
            e1 = (HEADS == 4) ? se[w][i1 * 4 + hd] : se[w][i1];
        } else {
            s1 = col[p + 2];
            float t = al_s[(size_t)s1 * HEADS + hd] + adh;
            e1 = (t >= 0.f) ? t : LRELU * t;
        }
        float a0 = __expf(e0 - mh);
        float a1 = __expf(e1 - mh);
        uint2 r0 = *(const uint2*)(hw + (size_t)s0 * 128 + c4);
        uint2 r1 = *(const uint2*)(hw + (size_t)s1 * 128 + c4);
        float2 f00 = __half22float2(*reinterpret_cast<__half2*>(&r0.x));
        float2 f01 = __half22float2(*reinterpret_cast<__half2*>(&r0.y));
        float2 f10 = __half22float2(*reinterpret_cast<__half2*>(&r1.x));
        float2 f11 = __half22float2(*reinterpret_cast<__half2*>(&r1.y));
        acc.x += a0 * f00.x + a1 * f10.x;
        acc.y += a0 * f00.y + a1 * f10.y;
        acc.z += a0 * f01.x + a1 * f11.x;
        acc.w += a0 * f01.y + a1 * f11.y;
    }
    if (p < end) {
        int i0 = p - start;
        int s0;
        float e0;
        if (i0 < CAP) {
            s0 = ss[w][i0];
            e0 = (HEADS == 4) ? se[w][i0 * 4 + hd] : se[w][i0];
        } else {
            s0 = col[p];
            float t = al_s[(size_t)s0 * HEADS + hd] + adh;
            e0 = (t >= 0.f) ? t : LRELU * t;
        }
        float a0 = __expf(e0 - mh);
        uint2 r0 = *(const uint2*)(hw + (size_t)s0 * 128 + c4);
        float2 f00 = __half22float2(*reinterpret_cast<__half2*>(&r0.x));
        float2 f01 = __half22float2(*reinterpret_cast<__half2*>(&r0.y));
        acc.x += a0 * f00.x;
        acc.y += a0 * f00.y;
        acc.z += a0 * f01.x;
        acc.w += a0 * f01.y;
    }
    // combine the two half-wave partial sums
    acc.x += __shfl_xor(acc.x, 32);
    acc.y += __shfl_xor(acc.y, 32);
    acc.z += __shfl_xor(acc.z, 32);
    acc.w += __shfl_xor(acc.w, 32);

    if (l < 32) {
        float4 g4 = *(const float4*)(gb + c4);
        float4 bg = *(const float4*)(bng + c4);
        float4 bbv = *(const float4*)(bnb + c4);
        float4 o;
        o.x = fmaxf((acc.x * invh + g4.x) * (bg.x * BN_INVS) + bbv.x, 0.f);
        o.y = fmaxf((acc.y * invh + g4.y) * (bg.y * BN_INVS) + bbv.y, 0.f);
        o.z = fmaxf((acc.z * invh + g4.z) * (bg.z * BN_INVS) + bbv.z, 0.f);
        o.w = fmaxf((acc.w * invh + g4.w) * (bg.w * BN_INVS) + bbv.w, 0.f);
        *(float4*)(hout + (size_t)v * 128 + c4) = o;
    }
}

// ---------------------------------------------------------------- platform branch -> c1 bias vector
__global__ void k_pconst(const float* __restrict__ px, const float* __restrict__ pW,
                         const float* __restrict__ pb, const float* __restrict__ c1W,
                         const float* __restrict__ c1b, float* __restrict__ cvec) {
    __shared__ float p[64];
    int t = threadIdx.x;  // 128 threads
    if (t < 64) {
        float s = pb[t];
#pragma unroll
        for (int i = 0; i < 4; ++i) s += px[i] * pW[i * 64 + t];
        p[t] = fmaxf(s, 0.f);
    }
    __syncthreads();
    if (t < 128) {
        float s = c1b[t];
#pragma unroll
        for (int j = 0; j < 64; ++j) s += p[j] * c1W[(128 + j) * 128 + t];
        cvec[t] = s;
    }
}

// ---------------------------------------------------------------- final classifier 64 -> 3
__global__ __launch_bounds__(256) void k_c3(const float* __restrict__ h5,
                                            const float* __restrict__ W,
                                            const float* __restrict__ b, float* __restrict__ out,
                                            int n) {
    __shared__ float Ws[192];
    __shared__ float bs[3];
    if (threadIdx.x < 192) Ws[threadIdx.x] = W[threadIdx.x];
    if (threadIdx.x < 3) bs[threadIdx.x] = b[threadIdx.x];
    __syncthreads();
    int v = blockIdx.x * 256 + threadIdx.x;
    if (v >= n) return;
    float a0 = bs[0], a1 = bs[1], a2 = bs[2];
#pragma unroll
    for (int k4 = 0; k4 < 16; ++k4) {
        float4 xv = *(const float4*)(h5 + (size_t)v * 64 + k4 * 4);
        int k = k4 * 4;
        a0 += xv.x * Ws[k * 3 + 0] + xv.y * Ws[k * 3 + 3] + xv.z * Ws[k * 3 + 6] + xv.w * Ws[k * 3 + 9];
        a1 += xv.x * Ws[k * 3 + 1] + xv.y * Ws[k * 3 + 4] + xv.z * Ws[k * 3 + 7] + xv.w * Ws[k * 3 + 10];
        a2 += xv.x * Ws[k * 3 + 2] + xv.y * Ws[k * 3 + 5] + xv.z * Ws[k * 3 + 8] + xv.w * Ws[k * 3 + 11];
    }
    out[v * 3 + 0] = a0;
    out[v * 3 + 1] = a1;
    out[v * 3 + 2] = a2;
}

// ================================================================ launch
extern "C" void kernel_launch(void* const* d_in, const int* in_sizes, int n_in,
                              void* d_out, int out_size, void* d_ws, size_t ws_size,
                              hipStream_t stream) {
    const float* x      = (const float*)d_in[0];
    const int*   ei     = (const int*)d_in[1];
    const float* px     = (const float*)d_in[2];
    const float* node_W = (const float*)d_in[3];
    const float* node_b = (const float*)d_in[4];
    const float* plat_W = (const float*)d_in[5];
    const float* plat_b = (const float*)d_in[6];
    const float* g1_W = (const float*)d_in[7];
    const float* g1_as = (const float*)d_in[8];
    const float* g1_ad = (const float*)d_in[9];
    const float* g1_b = (const float*)d_in[10];
    const float* g2_W = (const float*)d_in[11];
    const float* g2_as = (const float*)d_in[12];
    const float* g2_ad = (const float*)d_in[13];
    const float* g2_b = (const float*)d_in[14];
    const float* g3_W = (const float*)d_in[15];
    const float* g3_as = (const float*)d_in[16];
    const float* g3_ad = (const float*)d_in[17];
    const float* g3_b = (const float*)d_in[18];
    const float* bn1_g = (const float*)d_in[19];
    const float* bn1_b = (const float*)d_in[20];
    const float* bn2_g = (const float*)d_in[21];
    const float* bn2_b = (const float*)d_in[22];
    const float* bn3_g = (const float*)d_in[23];
    const float* bn3_b = (const float*)d_in[24];
    const float* c1_W = (const float*)d_in[25];
    const float* c1_b = (const float*)d_in[26];
    const float* c2_W = (const float*)d_in[27];
    const float* c2_b = (const float*)d_in[28];
    const float* c3_W = (const float*)d_in[29];
    const float* c3_b = (const float*)d_in[30];

    const int N = in_sizes[0] / 10;
    const int E = in_sizes[1] / 2;
    const int ET = E + N;  // edges incl. self loops

    // workspace carve-up (~60 MB; h16 aliases bufB which is dead during GAT layers)
    char* w = (char*)d_ws;
    auto alloc = [&](size_t bytes) {
        void* p = (void*)w;
        w += (bytes + 255) & ~(size_t)255;
        return p;
    };
    int*   col     = (int*)alloc((size_t)ET * 4);
    int*   deg     = (int*)alloc((size_t)N * 4);  // reused as scatter cursor
    int*   row_ptr = (int*)alloc((size_t)(N + 1) * 4);
    int*   bsum    = (int*)alloc(256 * 4);
    int*   boff    = (int*)alloc(256 * 4);
    float* al_s    = (float*)alloc((size_t)N * 4 * 4);
    float* al_d    = (float*)alloc((size_t)N * 4 * 4);
    float* bufA    = (float*)alloc((size_t)N * 128 * 4);
    float* bufB    = (float*)alloc((size_t)N * 128 * 4);
    float* cvec    = (float*)alloc(128 * 4);
    float* out     = (float*)d_out;
    __half* h16    = (__half*)bufB;  // alias: GAT-phase fp16 feature table (12.8 MB)

    const int NB = (N + 1023) / 1024;

    // ---- CSR build (dst-sorted; shared by all 3 GAT layers)
    k_initdeg<<<(N + 255) / 256, 256, 0, stream>>>(deg, N);
    k_count<<<(E + 255) / 256, 256, 0, stream>>>(ei, deg, E);
    k_scan1<<<NB, 1024, 0, stream>>>(deg, row_ptr, bsum, N);
    k_scan2<<<1, 64, 0, stream>>>(bsum, boff, NB);
    k_scan3<<<NB, 1024, 0, stream>>>(row_ptr, boff, N);
    k_cursor<<<(N + 255) / 256, 256, 0, stream>>>(row_ptr, deg, N);
    k_scatter<<<832, 256, 0, stream>>>(ei, deg, col, E, N);  // 8 XCD groups x 104 blocks

    // ---- node encoder
    k_node_enc<<<(N * 32 + 255) / 256, 256, 0, stream>>>(x, node_W, node_b, bufA, N);

    const int gGemm = (N + 127) / 128;
    const int gWave = (N * 64 + 255) / 256;  // one wave per node

    // ---- GAT layer 1 (heads=4): gemm bufA -> h16; softagg h16 -> bufA
    k_gemm128<128, false, false, true><<<gGemm, 256, 0, stream>>>(bufA, g1_W, nullptr, (float*)h16, N);
    k_al<4><<<gWave, 256, 0, stream>>>(h16, g1_as, g1_ad, al_s, al_d, N);
    k_softagg<4><<<gWave, 256, 0, stream>>>(row_ptr, col, al_s, al_d, h16, g1_b, bn1_g, bn1_b, bufA, N);

    // ---- GAT layer 2 (heads=4)
    k_gemm128<128, false, false, true><<<gGemm, 256, 0, stream>>>(bufA, g2_W, nullptr, (float*)h16, N);
    k_al<4><<<gWave, 256, 0, stream>>>(h16, g2_as, g2_ad, al_s, al_d, N);
    k_softagg<4><<<gWave, 256, 0, stream>>>(row_ptr, col, al_s, al_d, h16, g2_b, bn2_g, bn2_b, bufA, N);

    // ---- GAT layer 3 (heads=1)
    k_gemm128<128, false, false, true><<<gGemm, 256, 0, stream>>>(bufA, g3_W, nullptr, (float*)h16, N);
    k_al<1><<<gWave, 256, 0, stream>>>(h16, g3_as, g3_ad, al_s, al_d, N);
    k_softagg<1><<<gWave, 256, 0, stream>>>(row_ptr, col, al_s, al_d, h16, g3_b, bn3_g, bn3_b, bufA, N);

    // ---- platform branch folded into c1 bias
    k_pconst<<<1, 128, 0, stream>>>(px, plat_W, plat_b, c1_W, c1_b, cvec);

    // ---- classifier (bufA [N,128] -> bufB [N,128] -> bufA reused as [N,64] -> out)
    k_gemm128<128, true, true><<<gGemm, 256, 0, stream>>>(bufA, c1_W, cvec, bufB, N);
    k_gemm128<64, true, true><<<gGemm, 256, 0, stream>>>(bufB, c2_W, c2_b, bufA, N);
    k_c3<<<(N + 255) / 256, 256, 0, stream>>>(bufA, c3_W, c3_b, out, N);
}

// Round 9
// 720.619 us; speedup vs baseline: 1.2897x; 1.0251x over previous
//
#include <hip/hip_runtime.h>
#include <hip/hip_bf16.h>
#include <hip/hip_fp16.h>

#define LRELU 0.2f
#define BN_INVS 0.99999500003749968f  // 1/sqrt(1+1e-5)

// ---------------------------------------------------------------- CSR build
__global__ __launch_bounds__(256) void k_initdeg(int* deg, int n) {
    int i = blockIdx.x * 256 + threadIdx.x;
    if (i < n) deg[i] = 1;  // self-loop contributes 1
}

__global__ __launch_bounds__(256) void k_count(const int* __restrict__ ei, int* deg, int E) {
    int e = blockIdx.x * 256 + threadIdx.x;
    if (e < E) atomicAdd(&deg[ei[E + e]], 1);
}

__global__ __launch_bounds__(1024) void k_scan1(const int* __restrict__ deg, int* row_ptr,
                                                int* bsum, int n) {
    __shared__ int sm[1024];
    int t = threadIdx.x, g = blockIdx.x * 1024 + t;
    sm[t] = (g < n) ? deg[g] : 0;
    __syncthreads();
    for (int off = 1; off < 1024; off <<= 1) {
        int x = (t >= off) ? sm[t - off] : 0;
        __syncthreads();
        sm[t] += x;
        __syncthreads();
    }
    if (g < n) row_ptr[g + 1] = sm[t];
    if (t == 1023) bsum[blockIdx.x] = sm[t];
}

__global__ void k_scan2(const int* bsum, int* boff, int nb) {
    if (threadIdx.x == 0 && blockIdx.x == 0) {
        int s = 0;
        for (int i = 0; i < nb; ++i) { boff[i] = s; s += bsum[i]; }
    }
}

__global__ __launch_bounds__(1024) void k_scan3(int* row_ptr, const int* boff, int n) {
    int g = blockIdx.x * 1024 + threadIdx.x;
    if (g < n) row_ptr[g + 1] += boff[blockIdx.x];
    if (g == 0) row_ptr[0] = 0;
}

__global__ __launch_bounds__(256) void k_cursor(const int* __restrict__ rp, int* cur, int n) {
    int i = blockIdx.x * 256 + threadIdx.x;
    if (i < n) cur[i] = rp[i];
}

// XCD-range-partitioned scatter: group g = blockIdx&7 handles dst in [g*W, g*W+W).
__global__ __launch_bounds__(256) void k_scatter(const int* __restrict__ ei, int* cur, int* col,
                                                 int E, int n) {
    int g = blockIdx.x & 7;
    int W = (n + 7) >> 3;
    int lo = g * W;
    int hi = min(n, lo + W);
    int nb = gridDim.x >> 3;   // blocks per group
    int bi = blockIdx.x >> 3;  // block index within group
    int stride = nb * 256;
    for (int t = bi * 256 + threadIdx.x; t < E; t += stride) {
        int d = ei[E + t];
        if (d >= lo && d < hi) {
            int p = atomicAdd(&cur[d], 1);
            col[p] = ei[t];
        }
    }
    for (int v = lo + bi * 256 + threadIdx.x; v < hi; v += stride) {
        int p = atomicAdd(&cur[v], 1);
        col[p] = v;
    }
}

// ---------------------------------------------------------------- node encoder
__global__ __launch_bounds__(256) void k_node_enc(const float* __restrict__ x,
                                                  const float* __restrict__ W,
                                                  const float* __restrict__ b,
                                                  float* __restrict__ h, int n) {
    __shared__ float Ws[1280];
    __shared__ float bs[128];
    for (int i = threadIdx.x; i < 1280; i += 256) Ws[i] = W[i];
    if (threadIdx.x < 128) bs[threadIdx.x] = b[threadIdx.x];
    __syncthreads();
    int idx = blockIdx.x * 256 + threadIdx.x;  // over n*32
    if (idx >= n * 32) return;
    int v = idx >> 5, q = idx & 31;
    float xr[10];
#pragma unroll
    for (int i = 0; i < 10; ++i) xr[i] = x[v * 10 + i];
    float o[4];
#pragma unroll
    for (int j = 0; j < 4; ++j) {
        int c = q * 4 + j;
        float s = bs[c];
#pragma unroll
        for (int i = 0; i < 10; ++i) s += xr[i] * Ws[i * 128 + c];
        o[j] = fmaxf(s, 0.f);
    }
    *(float4*)(h + (size_t)v * 128 + q * 4) = make_float4(o[0], o[1], o[2], o[3]);
}

// ---------------------------------------------------------------- tiled fp32 GEMM, K=128
template <int M, bool ADD_BIAS, bool RELU, bool HALF_OUT = false>
__global__ __launch_bounds__(256) void k_gemm128(const float* __restrict__ A,
                                                 const float* __restrict__ B,
                                                 const float* __restrict__ bias,
                                                 float* __restrict__ C, int n) {
    constexpr int NG = M / 64;       // column groups of 64 (1 or 2)
    __shared__ float AsT[32][133];   // transposed A tile: [k][row]
    __shared__ float Bs[32][M];
    int tid = threadIdx.x;
    int row0 = blockIdx.x * 128;
    int ct = tid & 15, rt = tid >> 4;  // 16 col-threads x 16 row-threads
    float4 acc[8][NG];
#pragma unroll
    for (int i = 0; i < 8; ++i)
#pragma unroll
        for (int g = 0; g < NG; ++g) acc[i][g] = make_float4(0.f, 0.f, 0.f, 0.f);

    for (int kc = 0; kc < 128; kc += 32) {
#pragma unroll
        for (int i = 0; i < 4; ++i) {
            int f = tid + i * 256;       // 0..1023
            int r = f >> 3;              // 0..127
            int kq = (f & 7) * 4;        // 0..28
            float4 v = make_float4(0.f, 0.f, 0.f, 0.f);
            int gr = row0 + r;
            if (gr < n) v = *(const float4*)(A + (size_t)gr * 128 + kc + kq);
            AsT[kq + 0][r] = v.x;
            AsT[kq + 1][r] = v.y;
            AsT[kq + 2][r] = v.z;
            AsT[kq + 3][r] = v.w;
        }
#pragma unroll
        for (int i = 0; i < M / 32; ++i) {
            int f = tid + i * 256;
            int r = f / (M / 4), c4 = (f % (M / 4)) * 4;
            *(float4*)(&Bs[r][c4]) = *(const float4*)(B + (size_t)(kc + r) * M + c4);
        }
        __syncthreads();
#pragma unroll
        for (int k = 0; k < 32; ++k) {
            float4 a0 = *(const float4*)(&AsT[k][rt * 8]);
            float4 a1 = *(const float4*)(&AsT[k][rt * 8 + 4]);
            float av[8] = {a0.x, a0.y, a0.z, a0.w, a1.x, a1.y, a1.z, a1.w};
#pragma unroll
            for (int g = 0; g < NG; ++g) {
                float4 bv = *(const float4*)(&Bs[k][g * 64 + ct * 4]);
#pragma unroll
                for (int i = 0; i < 8; ++i) {
                    acc[i][g].x += av[i] * bv.x;
                    acc[i][g].y += av[i] * bv.y;
                    acc[i][g].z += av[i] * bv.z;
                    acc[i][g].w += av[i] * bv.w;
                }
            }
        }
        __syncthreads();
    }
    float4 bb[NG];
    if (ADD_BIAS) {
#pragma unroll
        for (int g = 0; g < NG; ++g) bb[g] = *(const float4*)(bias + g * 64 + ct * 4);
    }
#pragma unroll
    for (int i = 0; i < 8; ++i) {
        int gr = row0 + rt * 8 + i;
        if (gr < n) {
#pragma unroll
            for (int g = 0; g < NG; ++g) {
                float4 v = acc[i][g];
                if (ADD_BIAS) {
                    v.x += bb[g].x; v.y += bb[g].y; v.z += bb[g].z; v.w += bb[g].w;
                }
                if (RELU) {
                    v.x = fmaxf(v.x, 0.f); v.y = fmaxf(v.y, 0.f);
                    v.z = fmaxf(v.z, 0.f); v.w = fmaxf(v.w, 0.f);
                }
                if (HALF_OUT) {
                    __half hb[4];
                    hb[0] = __float2half(v.x);
                    hb[1] = __float2half(v.y);
                    hb[2] = __float2half(v.z);
                    hb[3] = __float2half(v.w);
                    __half* C16 = reinterpret_cast<__half*>(C);
                    *(ushort4*)(C16 + (size_t)gr * M + g * 64 + ct * 4) = *(ushort4*)hb;
                } else {
                    *(float4*)(C + (size_t)gr * M + g * 64 + ct * 4) = v;
                }
            }
        }
    }
}

// ---------------------------------------------------------------- attention logits per node (fp16 h)
template <int HEADS>
__global__ __launch_bounds__(256) void k_al(const __half* __restrict__ hw,
                                            const float* __restrict__ asrc,
                                            const float* __restrict__ adst,
                                            float* __restrict__ al_s, float* __restrict__ al_d,
                                            int n) {
    int wid = (blockIdx.x * 256 + threadIdx.x) >> 6;
    int l = threadIdx.x & 63;
    if (wid >= n) return;
    unsigned raw = *(const unsigned*)(hw + (size_t)wid * 128 + 2 * l);
    __half2 hp = *reinterpret_cast<__half2*>(&raw);
    float2 hv = __half22float2(hp);
    int c0 = 2 * l;
    if (HEADS == 4) {
        int h = l >> 4, dd = c0 & 31;
        float s = hv.x * asrc[h * 32 + dd] + hv.y * asrc[h * 32 + dd + 1];
        float d = hv.x * adst[h * 32 + dd] + hv.y * adst[h * 32 + dd + 1];
#pragma unroll
        for (int off = 1; off < 16; off <<= 1) {
            s += __shfl_xor(s, off);
            d += __shfl_xor(d, off);
        }
        if ((l & 15) == 0) {
            al_s[wid * 4 + h] = s;
            al_d[wid * 4 + h] = d;
        }
    } else {
        float s = hv.x * asrc[c0] + hv.y * asrc[c0 + 1];
        float d = hv.x * adst[c0] + hv.y * adst[c0 + 1];
#pragma unroll
        for (int off = 1; off < 64; off <<= 1) {
            s += __shfl_xor(s, off);
            d += __shfl_xor(d, off);
        }
        if (l == 0) {
            al_s[wid] = s;
            al_d[wid] = d;
        }
    }
}

// ------------------------------------------- fused segment softmax + aggregation + bias/BN/ReLU
// One wave per destination node. Fast path (deg<=CAP, wave-uniform): pass (a) gather
// logits -> LDS, plain max only; (b) LDS sweep converts e->alpha=exp(e-m), sums;
// (c) quarter-wave per edge (16 lanes x dwordx4 = full 256B fp16 row), fp32 accum.
// Slow path (deg>CAP, ~never): online softmax + half-wave recompute.
template <int HEADS>
__global__ __launch_bounds__(256) void k_softagg(const int* __restrict__ rp,
                                                 const int* __restrict__ col,
                                                 const float* __restrict__ al_s,
                                                 const float* __restrict__ al_d,
                                                 const __half* __restrict__ hw,
                                                 const float* __restrict__ gb,
                                                 const float* __restrict__ bng,
                                                 const float* __restrict__ bnb,
                                                 float* __restrict__ hout, int n) {
    constexpr int CAP = 128;
    __shared__ int ss[4][CAP];
    __shared__ __align__(16) float se[4][CAP * HEADS];
    int v = (blockIdx.x * 256 + threadIdx.x) >> 6;
    int l = threadIdx.x & 63;
    int w = threadIdx.x >> 6;  // wave within block
    if (v >= n) return;
    int start = rp[v], end = rp[v + 1];
    int deg = end - start;

    float ad[HEADS], m[HEADS], s[HEADS], inv[HEADS];
#pragma unroll
    for (int h = 0; h < HEADS; ++h) {
        ad[h] = al_d[v * HEADS + h];
        m[h] = -1e30f;
        s[h] = 0.f;
    }

    if (deg <= CAP) {
        // ---- (a) gather logits -> LDS, plain max
        for (int p = start + l; p < end; p += 64) {
            int src = col[p];
            float eh[HEADS];
            if (HEADS == 4) {
                float4 t4 = *(const float4*)(al_s + (size_t)src * 4);
                eh[0] = t4.x; eh[1] = t4.y; eh[2] = t4.z; eh[3] = t4.w;
            } else {
                eh[0] = al_s[src];
            }
#pragma unroll
            for (int h = 0; h < HEADS; ++h) {
                float e = eh[h] + ad[h];
                eh[h] = (e >= 0.f) ? e : LRELU * e;
                m[h] = fmaxf(m[h], eh[h]);
            }
            int idx = p - start;
            ss[w][idx] = src;
            if (HEADS == 4)
                *(float4*)(&se[w][idx * 4]) = make_float4(eh[0], eh[1], eh[2], eh[3]);
            else
                se[w][idx] = eh[0];
        }
#pragma unroll
        for (int off = 1; off < 64; off <<= 1)
#pragma unroll
            for (int h = 0; h < HEADS; ++h) m[h] = fmaxf(m[h], __shfl_xor(m[h], off));

        // ---- (b) e -> alpha in LDS, sum
        for (int idx = l; idx < deg; idx += 64) {
            if (HEADS == 4) {
                float4 e4 = *(float4*)(&se[w][idx * 4]);
                e4.x = __expf(e4.x - m[0]);
                e4.y = __expf(e4.y - m[1]);
                e4.z = __expf(e4.z - m[2]);
                e4.w = __expf(e4.w - m[3]);
                *(float4*)(&se[w][idx * 4]) = e4;
                s[0] += e4.x; s[1] += e4.y; s[2] += e4.z; s[3] += e4.w;
            } else {
                float a = __expf(se[w][idx] - m[0]);
                se[w][idx] = a;
                s[0] += a;
            }
        }
#pragma unroll
        for (int off = 1; off < 64; off <<= 1)
#pragma unroll
            for (int h = 0; h < HEADS; ++h) s[h] += __shfl_xor(s[h], off);
#pragma unroll
        for (int h = 0; h < HEADS; ++h) inv[h] = 1.f / (s[h] + 1e-16f);

        // ---- (c) quarter-wave aggregation: 16 lanes x 8 fp16 channels per edge
        int qe = l >> 4;       // edge slot 0..3
        int li = l & 15;       // channel lane
        int c8 = li * 8;
        int hd = (HEADS == 4) ? (li >> 2) : 0;
        float invh = inv[hd];
        float acc[8] = {0.f, 0.f, 0.f, 0.f, 0.f, 0.f, 0.f, 0.f};
        for (int p = start + qe; p < end; p += 4) {
            int idx = p - start;
            int s0 = ss[w][idx];
            float a0 = (HEADS == 4) ? se[w][idx * 4 + hd] : se[w][idx];
            uint4 r = *(const uint4*)(hw + (size_t)s0 * 128 + c8);
            float2 f0 = __half22float2(*reinterpret_cast<__half2*>(&r.x));
            float2 f1 = __half22float2(*reinterpret_cast<__half2*>(&r.y));
            float2 f2 = __half22float2(*reinterpret_cast<__half2*>(&r.z));
            float2 f3 = __half22float2(*reinterpret_cast<__half2*>(&r.w));
            acc[0] += a0 * f0.x; acc[1] += a0 * f0.y;
            acc[2] += a0 * f1.x; acc[3] += a0 * f1.y;
            acc[4] += a0 * f2.x; acc[5] += a0 * f2.y;
            acc[6] += a0 * f3.x; acc[7] += a0 * f3.y;
        }
#pragma unroll
        for (int j = 0; j < 8; ++j) {
            acc[j] += __shfl_xor(acc[j], 16);
            acc[j] += __shfl_xor(acc[j], 32);
        }
        if (l < 16) {
#pragma unroll
            for (int half = 0; half < 2; ++half) {
                int c4 = c8 + half * 4;
                float4 g4 = *(const float4*)(gb + c4);
                float4 bg = *(const float4*)(bng + c4);
                float4 bbv = *(const float4*)(bnb + c4);
                float4 o;
                o.x = fmaxf((acc[half * 4 + 0] * invh + g4.x) * (bg.x * BN_INVS) + bbv.x, 0.f);
                o.y = fmaxf((acc[half * 4 + 1] * invh + g4.y) * (bg.y * BN_INVS) + bbv.y, 0.f);
                o.z = fmaxf((acc[half * 4 + 2] * invh + g4.z) * (bg.z * BN_INVS) + bbv.z, 0.f);
                o.w = fmaxf((acc[half * 4 + 3] * invh + g4.w) * (bg.w * BN_INVS) + bbv.w, 0.f);
                *(float4*)(hout + (size_t)v * 128 + c4) = o;
            }
        }
        return;
    }

    // ---------------- slow path (deg > CAP): online softmax, recompute in pass 2
    for (int p = start + l; p < end; p += 64) {
        int src = col[p];
        float eh[HEADS];
        if (HEADS == 4) {
            float4 t4 = *(const float4*)(al_s + (size_t)src * 4);
            eh[0] = t4.x; eh[1] = t4.y; eh[2] = t4.z; eh[3] = t4.w;
        } else {
            eh[0] = al_s[src];
        }
#pragma unroll
        for (int h = 0; h < HEADS; ++h) {
            float e = eh[h] + ad[h];
            e = (e >= 0.f) ? e : LRELU * e;
            float nm = fmaxf(m[h], e);
            s[h] = s[h] * __expf(m[h] - nm) + __expf(e - nm);
            m[h] = nm;
        }
    }
#pragma unroll
    for (int off = 1; off < 64; off <<= 1) {
#pragma unroll
        for (int h = 0; h < HEADS; ++h) {
            float om = __shfl_xor(m[h], off), os = __shfl_xor(s[h], off);
            float nm = fmaxf(m[h], om);
            s[h] = s[h] * __expf(m[h] - nm) + os * __expf(om - nm);
            m[h] = nm;
        }
    }
#pragma unroll
    for (int h = 0; h < HEADS; ++h) inv[h] = 1.f / (s[h] + 1e-16f);

    int ew = l >> 5;
    int li = l & 31;
    int c4 = 4 * li;
    int hd = (HEADS == 4) ? (li >> 3) : 0;
    float mh = m[hd], invh = inv[hd], adh = ad[hd];
    float4 acc = make_float4(0.f, 0.f, 0.f, 0.f);
    for (int p = start + ew; p < end; p += 2) {
        int s0 = col[p];
        float t = al_s[(size_t)s0 * HEADS + hd] + adh;
        float e0 = (t >= 0.f) ? t : LRELU * t;
        float a0 = __expf(e0 - mh);
        uint2 r0 = *(const uint2*)(hw + (size_t)s0 * 128 + c4);
        float2 f00 = __half22float2(*reinterpret_cast<__half2*>(&r0.x));
        float2 f01 = __half22float2(*reinterpret_cast<__half2*>(&r0.y));
        acc.x += a0 * f00.x;
        acc.y += a0 * f00.y;
        acc.z += a0 * f01.x;
        acc.w += a0 * f01.y;
    }
    acc.x += __shfl_xor(acc.x, 32);
    acc.y += __shfl_xor(acc.y, 32);
    acc.z += __shfl_xor(acc.z, 32);
    acc.w += __shfl_xor(acc.w, 32);
    if (l < 32) {
        float4 g4 = *(const float4*)(gb + c4);
        float4 bg = *(const float4*)(bng + c4);
        float4 bbv = *(const float4*)(bnb + c4);
        float4 o;
        o.x = fmaxf((acc.x * invh + g4.x) * (bg.x * BN_INVS) + bbv.x, 0.f);
        o.y = fmaxf((acc.y * invh + g4.y) * (bg.y * BN_INVS) + bbv.y, 0.f);
        o.z = fmaxf((acc.z * invh + g4.z) * (bg.z * BN_INVS) + bbv.z, 0.f);
        o.w = fmaxf((acc.w * invh + g4.w) * (bg.w * BN_INVS) + bbv.w, 0.f);
        *(float4*)(hout + (size_t)v * 128 + c4) = o;
    }
}

// ---------------------------------------------------------------- platform branch -> c1 bias vector
__global__ void k_pconst(const float* __restrict__ px, const float* __restrict__ pW,
                         const float* __restrict__ pb, const float* __restrict__ c1W,
                         const float* __restrict__ c1b, float* __restrict__ cvec) {
    __shared__ float p[64];
    int t = threadIdx.x;  // 128 threads
    if (t < 64) {
        float s = pb[t];
#pragma unroll
        for (int i = 0; i < 4; ++i) s += px[i] * pW[i * 64 + t];
        p[t] = fmaxf(s, 0.f);
    }
    __syncthreads();
    if (t < 128) {
        float s = c1b[t];
#pragma unroll
        for (int j = 0; j < 64; ++j) s += p[j] * c1W[(128 + j) * 128 + t];
        cvec[t] = s;
    }
}

// ---------------------------------------------------------------- final classifier 64 -> 3
__global__ __launch_bounds__(256) void k_c3(const float* __restrict__ h5,
                                            const float* __restrict__ W,
                                            const float* __restrict__ b, float* __restrict__ out,
                                            int n) {
    __shared__ float Ws[192];
    __shared__ float bs[3];
    if (threadIdx.x < 192) Ws[threadIdx.x] = W[threadIdx.x];
    if (threadIdx.x < 3) bs[threadIdx.x] = b[threadIdx.x];
    __syncthreads();
    int v = blockIdx.x * 256 + threadIdx.x;
    if (v >= n) return;
    float a0 = bs[0], a1 = bs[1], a2 = bs[2];
#pragma unroll
    for (int k4 = 0; k4 < 16; ++k4) {
        float4 xv = *(const float4*)(h5 + (size_t)v * 64 + k4 * 4);
        int k = k4 * 4;
        a0 += xv.x * Ws[k * 3 + 0] + xv.y * Ws[k * 3 + 3] + xv.z * Ws[k * 3 + 6] + xv.w * Ws[k * 3 + 9];
        a1 += xv.x * Ws[k * 3 + 1] + xv.y * Ws[k * 3 + 4] + xv.z * Ws[k * 3 + 7] + xv.w * Ws[k * 3 + 10];
        a2 += xv.x * Ws[k * 3 + 2] + xv.y * Ws[k * 3 + 5] + xv.z * Ws[k * 3 + 8] + xv.w * Ws[k * 3 + 11];
    }
    out[v * 3 + 0] = a0;
    out[v * 3 + 1] = a1;
    out[v * 3 + 2] = a2;
}

// ================================================================ launch
extern "C" void kernel_launch(void* const* d_in, const int* in_sizes, int n_in,
                              void* d_out, int out_size, void* d_ws, size_t ws_size,
                              hipStream_t stream) {
    const float* x      = (const float*)d_in[0];
    const int*   ei     = (const int*)d_in[1];
    const float* px     = (const float*)d_in[2];
    const float* node_W = (const float*)d_in[3];
    const float* node_b = (const float*)d_in[4];
    const float* plat_W = (const float*)d_in[5];
    const float* plat_b = (const float*)d_in[6];
    const float* g1_W = (const float*)d_in[7];
    const float* g1_as = (const float*)d_in[8];
    const float* g1_ad = (const float*)d_in[9];
    const float* g1_b = (const float*)d_in[10];
    const float* g2_W = (const float*)d_in[11];
    const float* g2_as = (const float*)d_in[12];
    const float* g2_ad = (const float*)d_in[13];
    const float* g2_b = (const float*)d_in[14];
    const float* g3_W = (const float*)d_in[15];
    const float* g3_as = (const float*)d_in[16];
    const float* g3_ad = (const float*)d_in[17];
    const float* g3_b = (const float*)d_in[18];
    const float* bn1_g = (const float*)d_in[19];
    const float* bn1_b = (const float*)d_in[20];
    const float* bn2_g = (const float*)d_in[21];
    const float* bn2_b = (const float*)d_in[22];
    const float* bn3_g = (const float*)d_in[23];
    const float* bn3_b = (const float*)d_in[24];
    const float* c1_W = (const float*)d_in[25];
    const float* c1_b = (const float*)d_in[26];
    const float* c2_W = (const float*)d_in[27];
    const float* c2_b = (const float*)d_in[28];
    const float* c3_W = (const float*)d_in[29];
    const float* c3_b = (const float*)d_in[30];

    const int N = in_sizes[0] / 10;
    const int E = in_sizes[1] / 2;
    const int ET = E + N;  // edges incl. self loops

    // workspace carve-up (~60 MB; h16 aliases bufB which is dead during GAT layers)
    char* w = (char*)d_ws;
    auto alloc = [&](size_t bytes) {
        void* p = (void*)w;
        w += (bytes + 255) & ~(size_t)255;
        return p;
    };
    int*   col     = (int*)alloc((size_t)ET * 4);
    int*   deg     = (int*)alloc((size_t)N * 4);  // reused as scatter cursor
    int*   row_ptr = (int*)alloc((size_t)(N + 1) * 4);
    int*   bsum    = (int*)alloc(256 * 4);
    int*   boff    = (int*)alloc(256 * 4);
    float* al_s    = (float*)alloc((size_t)N * 4 * 4);
    float* al_d    = (float*)alloc((size_t)N * 4 * 4);
    float* bufA    = (float*)alloc((size_t)N * 128 * 4);
    float* bufB    = (float*)alloc((size_t)N * 128 * 4);
    float* cvec    = (float*)alloc(128 * 4);
    float* out     = (float*)d_out;
    __half* h16    = (__half*)bufB;  // alias: GAT-phase fp16 feature table (12.8 MB)

    const int NB = (N + 1023) / 1024;

    // ---- CSR build (dst-sorted; shared by all 3 GAT layers)
    k_initdeg<<<(N + 255) / 256, 256, 0, stream>>>(deg, N);
    k_count<<<(E + 255) / 256, 256, 0, stream>>>(ei, deg, E);
    k_scan1<<<NB, 1024, 0, stream>>>(deg, row_ptr, bsum, N);
    k_scan2<<<1, 64, 0, stream>>>(bsum, boff, NB);
    k_scan3<<<NB, 1024, 0, stream>>>(row_ptr, boff, N);
    k_cursor<<<(N + 255) / 256, 256, 0, stream>>>(row_ptr, deg, N);
    k_scatter<<<3328, 256, 0, stream>>>(ei, deg, col, E, N);  // 8 XCD groups x 416 blocks

    // ---- node encoder
    k_node_enc<<<(N * 32 + 255) / 256, 256, 0, stream>>>(x, node_W, node_b, bufA, N);

    const int gGemm = (N + 127) / 128;
    const int gWave = (N * 64 + 255) / 256;  // one wave per node

    // ---- GAT layer 1 (heads=4): gemm bufA -> h16; softagg h16 -> bufA
    k_gemm128<128, false, false, true><<<gGemm, 256, 0, stream>>>(bufA, g1_W, nullptr, (float*)h16, N);
    k_al<4><<<gWave, 256, 0, stream>>>(h16, g1_as, g1_ad, al_s, al_d, N);
    k_softagg<4><<<gWave, 256, 0, stream>>>(row_ptr, col, al_s, al_d, h16, g1_b, bn1_g, bn1_b, bufA, N);

    // ---- GAT layer 2 (heads=4)
    k_gemm128<128, false, false, true><<<gGemm, 256, 0, stream>>>(bufA, g2_W, nullptr, (float*)h16, N);
    k_al<4><<<gWave, 256, 0, stream>>>(h16, g2_as, g2_ad, al_s, al_d, N);
    k_softagg<4><<<gWave, 256, 0, stream>>>(row_ptr, col, al_s, al_d, h16, g2_b, bn2_g, bn2_b, bufA, N);

    // ---- GAT layer 3 (heads=1)
    k_gemm128<128, false, false, true><<<gGemm, 256, 0, stream>>>(bufA, g3_W, nullptr, (float*)h16, N);
    k_al<1><<<gWave, 256, 0, stream>>>(h16, g3_as, g3_ad, al_s, al_d, N);
    k_softagg<1><<<gWave, 256, 0, stream>>>(row_ptr, col, al_s, al_d, h16, g3_b, bn3_g, bn3_b, bufA, N);

    // ---- platform branch folded into c1 bias
    k_pconst<<<1, 128, 0, stream>>>(px, plat_W, plat_b, c1_W, c1_b, cvec);

    // ---- classifier (bufA [N,128] -> bufB [N,128] -> bufA reused as [N,64] -> out)
    k_gemm128<128, true, true><<<gGemm, 256, 0, stream>>>(bufA, c1_W, cvec, bufB, N);
    k_gemm128<64, true, true><<<gGemm, 256, 0, stream>>>(bufB, c2_W, c2_b, bufA, N);
    k_c3<<<(N + 255) / 256, 256, 0, stream>>>(bufA, c3_W, c3_b, out, N);
}

// Round 10
// 628.681 us; speedup vs baseline: 1.4783x; 1.1462x over previous
//
#include <hip/hip_runtime.h>
#include <hip/hip_bf16.h>
#include <hip/hip_fp16.h>

#define LRELU 0.2f
#define BN_INVS 0.99999500003749968f  // 1/sqrt(1+1e-5)

// ---------------------------------------------------------------- CSR build
__global__ __launch_bounds__(256) void k_initdeg(int* deg, int n) {
    int i = blockIdx.x * 256 + threadIdx.x;
    if (i < n) deg[i] = 1;  // self-loop contributes 1
}

__global__ __launch_bounds__(256) void k_count(const int* __restrict__ ei, int* deg, int E) {
    int e = blockIdx.x * 256 + threadIdx.x;
    if (e < E) atomicAdd(&deg[__builtin_nontemporal_load(&ei[E + e]) ? (ei[E + e]) : ei[E + e]], 1);
}

__global__ __launch_bounds__(1024) void k_scan1(const int* __restrict__ deg, int* row_ptr,
                                                int* bsum, int n) {
    __shared__ int sm[1024];
    int t = threadIdx.x, g = blockIdx.x * 1024 + t;
    sm[t] = (g < n) ? deg[g] : 0;
    __syncthreads();
    for (int off = 1; off < 1024; off <<= 1) {
        int x = (t >= off) ? sm[t - off] : 0;
        __syncthreads();
        sm[t] += x;
        __syncthreads();
    }
    if (g < n) row_ptr[g + 1] = sm[t];
    if (t == 1023) bsum[blockIdx.x] = sm[t];
}

__global__ void k_scan2(const int* bsum, int* boff, int nb) {
    if (threadIdx.x == 0 && blockIdx.x == 0) {
        int s = 0;
        for (int i = 0; i < nb; ++i) { boff[i] = s; s += bsum[i]; }
    }
}

__global__ __launch_bounds__(1024) void k_scan3(int* row_ptr, const int* boff, int n) {
    int g = blockIdx.x * 1024 + threadIdx.x;
    if (g < n) row_ptr[g + 1] += boff[blockIdx.x];
    if (g == 0) row_ptr[0] = 0;
}

__global__ __launch_bounds__(256) void k_cursor(const int* __restrict__ rp, int* cur, int n) {
    int i = blockIdx.x * 256 + threadIdx.x;
    if (i < n) cur[i] = rp[i];
}

// XCD-range-partitioned scatter: group g = blockIdx&7 handles dst in [g*W, g*W+W).
// Non-temporal ei loads keep the 13MB stream from evicting partially-assembled
// col write lines out of L2 (round-9 WRITE_SIZE=66MB diagnosis).
__global__ __launch_bounds__(256) void k_scatter(const int* __restrict__ ei, int* cur, int* col,
                                                 int E, int n) {
    int g = blockIdx.x & 7;
    int W = (n + 7) >> 3;
    int lo = g * W;
    int hi = min(n, lo + W);
    int nb = gridDim.x >> 3;   // blocks per group
    int bi = blockIdx.x >> 3;  // block index within group
    int stride = nb * 256;
    for (int t = bi * 256 + threadIdx.x; t < E; t += stride) {
        int d = __builtin_nontemporal_load(ei + E + t);
        if (d >= lo && d < hi) {
            int s = __builtin_nontemporal_load(ei + t);
            int p = atomicAdd(&cur[d], 1);
            col[p] = s;
        }
    }
    for (int v = lo + bi * 256 + threadIdx.x; v < hi; v += stride) {
        int p = atomicAdd(&cur[v], 1);
        col[p] = v;
    }
}

// ---------------------------------------------------------------- node encoder
__global__ __launch_bounds__(256) void k_node_enc(const float* __restrict__ x,
                                                  const float* __restrict__ W,
                                                  const float* __restrict__ b,
                                                  float* __restrict__ h, int n) {
    __shared__ float Ws[1280];
    __shared__ float bs[128];
    for (int i = threadIdx.x; i < 1280; i += 256) Ws[i] = W[i];
    if (threadIdx.x < 128) bs[threadIdx.x] = b[threadIdx.x];
    __syncthreads();
    int idx = blockIdx.x * 256 + threadIdx.x;  // over n*32
    if (idx >= n * 32) return;
    int v = idx >> 5, q = idx & 31;
    float xr[10];
#pragma unroll
    for (int i = 0; i < 10; ++i) xr[i] = x[v * 10 + i];
    float o[4];
#pragma unroll
    for (int j = 0; j < 4; ++j) {
        int c = q * 4 + j;
        float s = bs[c];
#pragma unroll
        for (int i = 0; i < 10; ++i) s += xr[i] * Ws[i * 128 + c];
        o[j] = fmaxf(s, 0.f);
    }
    *(float4*)(h + (size_t)v * 128 + q * 4) = make_float4(o[0], o[1], o[2], o[3]);
}

// ---------------------------------------------------------------- tiled fp32 GEMM, K=128
// 64x64 tile, 4x4/thread, grid (ceil(n/64), M/64). Small tile => 1564 blocks for
// N=50000/M=128 => ~6 blocks/CU (vs 391 blocks / 8% occupancy at 128x128 tile).
template <int M, bool ADD_BIAS, bool RELU, bool HALF_OUT = false>
__global__ __launch_bounds__(256) void k_gemm64(const float* __restrict__ A,
                                                const float* __restrict__ B,
                                                const float* __restrict__ bias,
                                                float* __restrict__ C, int n) {
    __shared__ float AsT[32][68];  // [k][row], pad 68: b128-aligned rows, 2-way-free reads
    __shared__ float Bs[32][68];
    int tid = threadIdx.x;
    int row0 = blockIdx.x * 64;
    int col0 = blockIdx.y * 64;
    int ct = tid & 15, rt = tid >> 4;  // 16 col-threads x 16 row-threads
    float4 acc[4];
#pragma unroll
    for (int i = 0; i < 4; ++i) acc[i] = make_float4(0.f, 0.f, 0.f, 0.f);

    for (int kc = 0; kc < 128; kc += 32) {
        // stage A (64 rows x 32 k), transposed
#pragma unroll
        for (int i = 0; i < 2; ++i) {
            int f = tid + i * 256;       // 0..511
            int r = f >> 3;              // 0..63
            int kq = (f & 7) * 4;        // 0..28
            float4 v = make_float4(0.f, 0.f, 0.f, 0.f);
            int gr = row0 + r;
            if (gr < n) v = *(const float4*)(A + (size_t)gr * 128 + kc + kq);
            AsT[kq + 0][r] = v.x;
            AsT[kq + 1][r] = v.y;
            AsT[kq + 2][r] = v.z;
            AsT[kq + 3][r] = v.w;
        }
        // stage B (32 k x 64 cols)
#pragma unroll
        for (int i = 0; i < 2; ++i) {
            int f = tid + i * 256;       // 0..511
            int r = f >> 4;              // 0..31
            int c4 = (f & 15) * 4;       // 0..60
            *(float4*)(&Bs[r][c4]) = *(const float4*)(B + (size_t)(kc + r) * M + col0 + c4);
        }
        __syncthreads();
#pragma unroll
        for (int k = 0; k < 32; ++k) {
            float4 av = *(const float4*)(&AsT[k][rt * 4]);
            float4 bv = *(const float4*)(&Bs[k][ct * 4]);
            acc[0].x += av.x * bv.x; acc[0].y += av.x * bv.y; acc[0].z += av.x * bv.z; acc[0].w += av.x * bv.w;
            acc[1].x += av.y * bv.x; acc[1].y += av.y * bv.y; acc[1].z += av.y * bv.z; acc[1].w += av.y * bv.w;
            acc[2].x += av.z * bv.x; acc[2].y += av.z * bv.y; acc[2].z += av.z * bv.z; acc[2].w += av.z * bv.w;
            acc[3].x += av.w * bv.x; acc[3].y += av.w * bv.y; acc[3].z += av.w * bv.z; acc[3].w += av.w * bv.w;
        }
        __syncthreads();
    }
    float4 bb = make_float4(0.f, 0.f, 0.f, 0.f);
    if (ADD_BIAS) bb = *(const float4*)(bias + col0 + ct * 4);
#pragma unroll
    for (int i = 0; i < 4; ++i) {
        int gr = row0 + rt * 4 + i;
        if (gr < n) {
            float4 v = acc[i];
            if (ADD_BIAS) {
                v.x += bb.x; v.y += bb.y; v.z += bb.z; v.w += bb.w;
            }
            if (RELU) {
                v.x = fmaxf(v.x, 0.f); v.y = fmaxf(v.y, 0.f);
                v.z = fmaxf(v.z, 0.f); v.w = fmaxf(v.w, 0.f);
            }
            if (HALF_OUT) {
                __half hb[4];
                hb[0] = __float2half(v.x);
                hb[1] = __float2half(v.y);
                hb[2] = __float2half(v.z);
                hb[3] = __float2half(v.w);
                __half* C16 = reinterpret_cast<__half*>(C);
                *(ushort4*)(C16 + (size_t)gr * M + col0 + ct * 4) = *(ushort4*)hb;
            } else {
                *(float4*)(C + (size_t)gr * M + col0 + ct * 4) = v;
            }
        }
    }
}

// ---------------------------------------------------------------- attention logits per node (fp16 h)
template <int HEADS>
__global__ __launch_bounds__(256) void k_al(const __half* __restrict__ hw,
                                            const float* __restrict__ asrc,
                                            const float* __restrict__ adst,
                                            float* __restrict__ al_s, float* __restrict__ al_d,
                                            int n) {
    int wid = (blockIdx.x * 256 + threadIdx.x) >> 6;
    int l = threadIdx.x & 63;
    if (wid >= n) return;
    unsigned raw = *(const unsigned*)(hw + (size_t)wid * 128 + 2 * l);
    __half2 hp = *reinterpret_cast<__half2*>(&raw);
    float2 hv = __half22float2(hp);
    int c0 = 2 * l;
    if (HEADS == 4) {
        int h = l >> 4, dd = c0 & 31;
        float s = hv.x * asrc[h * 32 + dd] + hv.y * asrc[h * 32 + dd + 1];
        float d = hv.x * adst[h * 32 + dd] + hv.y * adst[h * 32 + dd + 1];
#pragma unroll
        for (int off = 1; off < 16; off <<= 1) {
            s += __shfl_xor(s, off);
            d += __shfl_xor(d, off);
        }
        if ((l & 15) == 0) {
            al_s[wid * 4 + h] = s;
            al_d[wid * 4 + h] = d;
        }
    } else {
        float s = hv.x * asrc[c0] + hv.y * asrc[c0 + 1];
        float d = hv.x * adst[c0] + hv.y * adst[c0 + 1];
#pragma unroll
        for (int off = 1; off < 64; off <<= 1) {
            s += __shfl_xor(s, off);
            d += __shfl_xor(d, off);
        }
        if (l == 0) {
            al_s[wid] = s;
            al_d[wid] = d;
        }
    }
}

// ------------------------------------------- fused segment softmax + aggregation + bias/BN/ReLU
template <int HEADS>
__global__ __launch_bounds__(256) void k_softagg(const int* __restrict__ rp,
                                                 const int* __restrict__ col,
                                                 const float* __restrict__ al_s,
                                                 const float* __restrict__ al_d,
                                                 const __half* __restrict__ hw,
                                                 const float* __restrict__ gb,
                                                 const float* __restrict__ bng,
                                                 const float* __restrict__ bnb,
                                                 float* __restrict__ hout, int n) {
    constexpr int CAP = 128;
    __shared__ int ss[4][CAP];
    __shared__ __align__(16) float se[4][CAP * HEADS];
    int v = (blockIdx.x * 256 + threadIdx.x) >> 6;
    int l = threadIdx.x & 63;
    int w = threadIdx.x >> 6;  // wave within block
    if (v >= n) return;
    int start = rp[v], end = rp[v + 1];
    int deg = end - start;

    float ad[HEADS], m[HEADS], s[HEADS], inv[HEADS];
#pragma unroll
    for (int h = 0; h < HEADS; ++h) {
        ad[h] = al_d[v * HEADS + h];
        m[h] = -1e30f;
        s[h] = 0.f;
    }

    if (deg <= CAP) {
        // ---- (a) gather logits -> LDS, plain max
        for (int p = start + l; p < end; p += 64) {
            int src = col[p];
            float eh[HEADS];
            if (HEADS == 4) {
                float4 t4 = *(const float4*)(al_s + (size_t)src * 4);
                eh[0] = t4.x; eh[1] = t4.y; eh[2] = t4.z; eh[3] = t4.w;
            } else {
                eh[0] = al_s[src];
            }
#pragma unroll
            for (int h = 0; h < HEADS; ++h) {
                float e = eh[h] + ad[h];
                eh[h] = (e >= 0.f) ? e : LRELU * e;
                m[h] = fmaxf(m[h], eh[h]);
            }
            int idx = p - start;
            ss[w][idx] = src;
            if (HEADS == 4)
                *(float4*)(&se[w][idx * 4]) = make_float4(eh[0], eh[1], eh[2], eh[3]);
            else
                se[w][idx] = eh[0];
        }
#pragma unroll
        for (int off = 1; off < 64; off <<= 1)
#pragma unroll
            for (int h = 0; h < HEADS; ++h) m[h] = fmaxf(m[h], __shfl_xor(m[h], off));

        // ---- (b) e -> alpha in LDS, sum
        for (int idx = l; idx < deg; idx += 64) {
            if (HEADS == 4) {
                float4 e4 = *(float4*)(&se[w][idx * 4]);
                e4.x = __expf(e4.x - m[0]);
                e4.y = __expf(e4.y - m[1]);
                e4.z = __expf(e4.z - m[2]);
                e4.w = __expf(e4.w - m[3]);
                *(float4*)(&se[w][idx * 4]) = e4;
                s[0] += e4.x; s[1] += e4.y; s[2] += e4.z; s[3] += e4.w;
            } else {
                float a = __expf(se[w][idx] - m[0]);
                se[w][idx] = a;
                s[0] += a;
            }
        }
#pragma unroll
        for (int off = 1; off < 64; off <<= 1)
#pragma unroll
            for (int h = 0; h < HEADS; ++h) s[h] += __shfl_xor(s[h], off);
#pragma unroll
        for (int h = 0; h < HEADS; ++h) inv[h] = 1.f / (s[h] + 1e-16f);

        // ---- (c) quarter-wave aggregation: 16 lanes x 8 fp16 channels per edge
        int qe = l >> 4;       // edge slot 0..3
        int li = l & 15;       // channel lane
        int c8 = li * 8;
        int hd = (HEADS == 4) ? (li >> 2) : 0;
        float invh = inv[hd];
        float acc[8] = {0.f, 0.f, 0.f, 0.f, 0.f, 0.f, 0.f, 0.f};
        for (int p = start + qe; p < end; p += 4) {
            int idx = p - start;
            int s0 = ss[w][idx];
            float a0 = (HEADS == 4) ? se[w][idx * 4 + hd] : se[w][idx];
            uint4 r = *(const uint4*)(hw + (size_t)s0 * 128 + c8);
            float2 f0 = __half22float2(*reinterpret_cast<__half2*>(&r.x));
            float2 f1 = __half22float2(*reinterpret_cast<__half2*>(&r.y));
            float2 f2 = __half22float2(*reinterpret_cast<__half2*>(&r.z));
            float2 f3 = __half22float2(*reinterpret_cast<__half2*>(&r.w));
            acc[0] += a0 * f0.x; acc[1] += a0 * f0.y;
            acc[2] += a0 * f1.x; acc[3] += a0 * f1.y;
            acc[4] += a0 * f2.x; acc[5] += a0 * f2.y;
            acc[6] += a0 * f3.x; acc[7] += a0 * f3.y;
        }
#pragma unroll
        for (int j = 0; j < 8; ++j) {
            acc[j] += __shfl_xor(acc[j], 16);
            acc[j] += __shfl_xor(acc[j], 32);
        }
        if (l < 16) {
#pragma unroll
            for (int half = 0; half < 2; ++half) {
                int c4 = c8 + half * 4;
                float4 g4 = *(const float4*)(gb + c4);
                float4 bg = *(const float4*)(bng + c4);
                float4 bbv = *(const float4*)(bnb + c4);
                float4 o;
                o.x = fmaxf((acc[half * 4 + 0] * invh + g4.x) * (bg.x * BN_INVS) + bbv.x, 0.f);
                o.y = fmaxf((acc[half * 4 + 1] * invh + g4.y) * (bg.y * BN_INVS) + bbv.y, 0.f);
                o.z = fmaxf((acc[half * 4 + 2] * invh + g4.z) * (bg.z * BN_INVS) + bbv.z, 0.f);
                o.w = fmaxf((acc[half * 4 + 3] * invh + g4.w) * (bg.w * BN_INVS) + bbv.w, 0.f);
                *(float4*)(hout + (size_t)v * 128 + c4) = o;
            }
        }
        return;
    }

    // ---------------- slow path (deg > CAP): online softmax, recompute in pass 2
    for (int p = start + l; p < end; p += 64) {
        int src = col[p];
        float eh[HEADS];
        if (HEADS == 4) {
            float4 t4 = *(const float4*)(al_s + (size_t)src * 4);
            eh[0] = t4.x; eh[1] = t4.y; eh[2] = t4.z; eh[3] = t4.w;
        } else {
            eh[0] = al_s[src];
        }
#pragma unroll
        for (int h = 0; h < HEADS; ++h) {
            float e = eh[h] + ad[h];
            e = (e >= 0.f) ? e : LRELU * e;
            float nm = fmaxf(m[h], e);
            s[h] = s[h] * __expf(m[h] - nm) + __expf(e - nm);
            m[h] = nm;
        }
    }
#pragma unroll
    for (int off = 1; off < 64; off <<= 1) {
#pragma unroll
        for (int h = 0; h < HEADS; ++h) {
            float om = __shfl_xor(m[h], off), os = __shfl_xor(s[h], off);
            float nm = fmaxf(m[h], om);
            s[h] = s[h] * __expf(m[h] - nm) + os * __expf(om - nm);
            m[h] = nm;
        }
    }
#pragma unroll
    for (int h = 0; h < HEADS; ++h) inv[h] = 1.f / (s[h] + 1e-16f);

    int ew = l >> 5;
    int li = l & 31;
    int c4 = 4 * li;
    int hd = (HEADS == 4) ? (li >> 3) : 0;
    float mh = m[hd], invh = inv[hd], adh = ad[hd];
    float4 acc = make_float4(0.f, 0.f, 0.f, 0.f);
    for (int p = start + ew; p < end; p += 2) {
        int s0 = col[p];
        float t = al_s[(size_t)s0 * HEADS + hd] + adh;
        float e0 = (t >= 0.f) ? t : LRELU * t;
        float a0 = __expf(e0 - mh);
        uint2 r0 = *(const uint2*)(hw + (size_t)s0 * 128 + c4);
        float2 f00 = __half22float2(*reinterpret_cast<__half2*>(&r0.x));
        float2 f01 = __half22float2(*reinterpret_cast<__half2*>(&r0.y));
        acc.x += a0 * f00.x;
        acc.y += a0 * f00.y;
        acc.z += a0 * f01.x;
        acc.w += a0 * f01.y;
    }
    acc.x += __shfl_xor(acc.x, 32);
    acc.y += __shfl_xor(acc.y, 32);
    acc.z += __shfl_xor(acc.z, 32);
    acc.w += __shfl_xor(acc.w, 32);
    if (l < 32) {
        float4 g4 = *(const float4*)(gb + c4);
        float4 bg = *(const float4*)(bng + c4);
        float4 bbv = *(const float4*)(bnb + c4);
        float4 o;
        o.x = fmaxf((acc.x * invh + g4.x) * (bg.x * BN_INVS) + bbv.x, 0.f);
        o.y = fmaxf((acc.y * invh + g4.y) * (bg.y * BN_INVS) + bbv.y, 0.f);
        o.z = fmaxf((acc.z * invh + g4.z) * (bg.z * BN_INVS) + bbv.z, 0.f);
        o.w = fmaxf((acc.w * invh + g4.w) * (bg.w * BN_INVS) + bbv.w, 0.f);
        *(float4*)(hout + (size_t)v * 128 + c4) = o;
    }
}

// ---------------------------------------------------------------- platform branch -> c1 bias vector
__global__ void k_pconst(const float* __restrict__ px, const float* __restrict__ pW,
                         const float* __restrict__ pb, const float* __restrict__ c1W,
                         const float* __restrict__ c1b, float* __restrict__ cvec) {
    __shared__ float p[64];
    int t = threadIdx.x;  // 128 threads
    if (t < 64) {
        float s = pb[t];
#pragma unroll
        for (int i = 0; i < 4; ++i) s += px[i] * pW[i * 64 + t];
        p[t] = fmaxf(s, 0.f);
    }
    __syncthreads();
    if (t < 128) {
        float s = c1b[t];
#pragma unroll
        for (int j = 0; j < 64; ++j) s += p[j] * c1W[(128 + j) * 128 + t];
        cvec[t] = s;
    }
}

// ---------------------------------------------------------------- final classifier 64 -> 3
__global__ __launch_bounds__(256) void k_c3(const float* __restrict__ h5,
                                            const float* __restrict__ W,
                                            const float* __restrict__ b, float* __restrict__ out,
                                            int n) {
    __shared__ float Ws[192];
    __shared__ float bs[3];
    if (threadIdx.x < 192) Ws[threadIdx.x] = W[threadIdx.x];
    if (threadIdx.x < 3) bs[threadIdx.x] = b[threadIdx.x];
    __syncthreads();
    int v = blockIdx.x * 256 + threadIdx.x;
    if (v >= n) return;
    float a0 = bs[0], a1 = bs[1], a2 = bs[2];
#pragma unroll
    for (int k4 = 0; k4 < 16; ++k4) {
        float4 xv = *(const float4*)(h5 + (size_t)v * 64 + k4 * 4);
        int k = k4 * 4;
        a0 += xv.x * Ws[k * 3 + 0] + xv.y * Ws[k * 3 + 3] + xv.z * Ws[k * 3 + 6] + xv.w * Ws[k * 3 + 9];
        a1 += xv.x * Ws[k * 3 + 1] + xv.y * Ws[k * 3 + 4] + xv.z * Ws[k * 3 + 7] + xv.w * Ws[k * 3 + 10];
        a2 += xv.x * Ws[k * 3 + 2] + xv.y * Ws[k * 3 + 5] + xv.z * Ws[k * 3 + 8] + xv.w * Ws[k * 3 + 11];
    }
    out[v * 3 + 0] = a0;
    out[v * 3 + 1] = a1;
    out[v * 3 + 2] = a2;
}

// ================================================================ launch
extern "C" void kernel_launch(void* const* d_in, const int* in_sizes, int n_in,
                              void* d_out, int out_size, void* d_ws, size_t ws_size,
                              hipStream_t stream) {
    const float* x      = (const float*)d_in[0];
    const int*   ei     = (const int*)d_in[1];
    const float* px     = (const float*)d_in[2];
    const float* node_W = (const float*)d_in[3];
    const float* node_b = (const float*)d_in[4];
    const float* plat_W = (const float*)d_in[5];
    const float* plat_b = (const float*)d_in[6];
    const float* g1_W = (const float*)d_in[7];
    const float* g1_as = (const float*)d_in[8];
    const float* g1_ad = (const float*)d_in[9];
    const float* g1_b = (const float*)d_in[10];
    const float* g2_W = (const float*)d_in[11];
    const float* g2_as = (const float*)d_in[12];
    const float* g2_ad = (const float*)d_in[13];
    const float* g2_b = (const float*)d_in[14];
    const float* g3_W = (const float*)d_in[15];
    const float* g3_as = (const float*)d_in[16];
    const float* g3_ad = (const float*)d_in[17];
    const float* g3_b = (const float*)d_in[18];
    const float* bn1_g = (const float*)d_in[19];
    const float* bn1_b = (const float*)d_in[20];
    const float* bn2_g = (const float*)d_in[21];
    const float* bn2_b = (const float*)d_in[22];
    const float* bn3_g = (const float*)d_in[23];
    const float* bn3_b = (const float*)d_in[24];
    const float* c1_W = (const float*)d_in[25];
    const float* c1_b = (const float*)d_in[26];
    const float* c2_W = (const float*)d_in[27];
    const float* c2_b = (const float*)d_in[28];
    const float* c3_W = (const float*)d_in[29];
    const float* c3_b = (const float*)d_in[30];

    const int N = in_sizes[0] / 10;
    const int E = in_sizes[1] / 2;
    const int ET = E + N;  // edges incl. self loops

    // workspace carve-up (~60 MB; h16 aliases bufB which is dead during GAT layers)
    char* w = (char*)d_ws;
    auto alloc = [&](size_t bytes) {
        void* p = (void*)w;
        w += (bytes + 255) & ~(size_t)255;
        return p;
    };
    int*   col     = (int*)alloc((size_t)ET * 4);
    int*   deg     = (int*)alloc((size_t)N * 4);  // reused as scatter cursor
    int*   row_ptr = (int*)alloc((size_t)(N + 1) * 4);
    int*   bsum    = (int*)alloc(256 * 4);
    int*   boff    = (int*)alloc(256 * 4);
    float* al_s    = (float*)alloc((size_t)N * 4 * 4);
    float* al_d    = (float*)alloc((size_t)N * 4 * 4);
    float* bufA    = (float*)alloc((size_t)N * 128 * 4);
    float* bufB    = (float*)alloc((size_t)N * 128 * 4);
    float* cvec    = (float*)alloc(128 * 4);
    float* out     = (float*)d_out;
    __half* h16    = (__half*)bufB;  // alias: GAT-phase fp16 feature table (12.8 MB)

    const int NB = (N + 1023) / 1024;

    // ---- CSR build (dst-sorted; shared by all 3 GAT layers)
    k_initdeg<<<(N + 255) / 256, 256, 0, stream>>>(deg, N);
    k_count<<<(E + 255) / 256, 256, 0, stream>>>(ei, deg, E);
    k_scan1<<<NB, 1024, 0, stream>>>(deg, row_ptr, bsum, N);
    k_scan2<<<1, 64, 0, stream>>>(bsum, boff, NB);
    k_scan3<<<NB, 1024, 0, stream>>>(row_ptr, boff, N);
    k_cursor<<<(N + 255) / 256, 256, 0, stream>>>(row_ptr, deg, N);
    k_scatter<<<3328, 256, 0, stream>>>(ei, deg, col, E, N);  // 8 XCD groups x 416 blocks

    // ---- node encoder
    k_node_enc<<<(N * 32 + 255) / 256, 256, 0, stream>>>(x, node_W, node_b, bufA, N);

    const dim3 g128((N + 63) / 64, 2);  // 64x64 tiles, M=128
    const dim3 g64((N + 63) / 64, 1);   // M=64
    const int gWave = (N * 64 + 255) / 256;  // one wave per node

    // ---- GAT layer 1 (heads=4): gemm bufA -> h16; softagg h16 -> bufA
    k_gemm64<128, false, false, true><<<g128, 256, 0, stream>>>(bufA, g1_W, nullptr, (float*)h16, N);
    k_al<4><<<gWave, 256, 0, stream>>>(h16, g1_as, g1_ad, al_s, al_d, N);
    k_softagg<4><<<gWave, 256, 0, stream>>>(row_ptr, col, al_s, al_d, h16, g1_b, bn1_g, bn1_b, bufA, N);

    // ---- GAT layer 2 (heads=4)
    k_gemm64<128, false, false, true><<<g128, 256, 0, stream>>>(bufA, g2_W, nullptr, (float*)h16, N);
    k_al<4><<<gWave, 256, 0, stream>>>(h16, g2_as, g2_ad, al_s, al_d, N);
    k_softagg<4><<<gWave, 256, 0, stream>>>(row_ptr, col, al_s, al_d, h16, g2_b, bn2_g, bn2_b, bufA, N);

    // ---- GAT layer 3 (heads=1)
    k_gemm64<128, false, false, true><<<g128, 256, 0, stream>>>(bufA, g3_W, nullptr, (float*)h16, N);
    k_al<1><<<gWave, 256, 0, stream>>>(h16, g3_as, g3_ad, al_s, al_d, N);
    k_softagg<1><<<gWave, 256, 0, stream>>>(row_ptr, col, al_s, al_d, h16, g3_b, bn3_g, bn3_b, bufA, N);

    // ---- platform branch folded into c1 bias
    k_pconst<<<1, 128, 0, stream>>>(px, plat_W, plat_b, c1_W, c1_b, cvec);

    // ---- classifier (bufA [N,128] -> bufB [N,128] -> bufA reused as [N,64] -> out)
    k_gemm64<128, true, true><<<g128, 256, 0, stream>>>(bufA, c1_W, cvec, bufB, N);
    k_gemm64<64, true, true><<<g64, 256, 0, stream>>>(bufB, c2_W, c2_b, bufA, N);
    k_c3<<<(N + 255) / 256, 256, 0, stream>>>(bufA, c3_W, c3_b, out, N);
}